// Round 9
// baseline (143.369 us; speedup 1.0000x reference)
//
#include <hip/hip_runtime.h>

#define Bv 2
#define Nv 5000
#define Cv 768
#define Hv 12
#define Dv 64
#define Ev 160000
#define ETOT (Ev + Nv)   // 165000 (edges + self loops)
#define HD 768
#define NEG 0.2f
#define Mv (Bv * Nv)     // 10000
#define MPAD 10240       // 40 * 256
#define DEGMAX 128       // max in-degree incl. self-loop; Poisson(33) tail -> safe

typedef __bf16 bf16x8 __attribute__((ext_vector_type(8)));
typedef float f32x4 __attribute__((ext_vector_type(4)));

// direct-to-LDS 16B async copy
#define GLD16(gsrc, ldst)                                                      \
  __builtin_amdgcn_global_load_lds(                                            \
      (const __attribute__((address_space(1))) unsigned int*)(gsrc),           \
      (__attribute__((address_space(3))) unsigned int*)(ldst), 16, 0, 0)

// f32 -> bf16 round-to-nearest-even
__device__ __forceinline__ unsigned short f2b(float f) {
  unsigned u = __float_as_uint(f);
  return (unsigned short)((u + 0x7FFFu + ((u >> 16) & 1u)) >> 16);
}
__device__ __forceinline__ float b2f(unsigned short b) {
  return __uint_as_float((unsigned)b << 16);
}

// ---------------- convert x -> bf16, padded to MPAD rows -------------------
__global__ __launch_bounds__(256) void k_cvt_x(const float* __restrict__ x,
                                               unsigned short* __restrict__ xb) {
  size_t i = ((size_t)blockIdx.x * 256 + threadIdx.x) * 8;
  if (i >= (size_t)MPAD * Cv) return;
  unsigned short o[8];
  if (i < (size_t)Mv * Cv) {
    float4 v0 = *(const float4*)(x + i);
    float4 v1 = *(const float4*)(x + i + 4);
    o[0] = f2b(v0.x); o[1] = f2b(v0.y); o[2] = f2b(v0.z); o[3] = f2b(v0.w);
    o[4] = f2b(v1.x); o[5] = f2b(v1.y); o[6] = f2b(v1.z); o[7] = f2b(v1.w);
  } else {
    for (int j = 0; j < 8; ++j) o[j] = 0;
  }
  *(uint4*)(xb + i) = *(const uint4*)o;
}

// ---------------- transpose+convert W[k][n] -> Wt[n][k] bf16 ---------------
__global__ __launch_bounds__(256) void k_cvt_wt(const float* __restrict__ W,
                                                unsigned short* __restrict__ Wt) {
  __shared__ float s[32][33];
  const int k0 = blockIdx.y * 32, n0 = blockIdx.x * 32;
  const int tx = threadIdx.x, ty = threadIdx.y;  // 32 x 8
#pragma unroll
  for (int i = 0; i < 4; ++i)
    s[ty + i * 8][tx] = W[(size_t)(k0 + ty + i * 8) * HD + n0 + tx];
  __syncthreads();
#pragma unroll
  for (int i = 0; i < 4; ++i)
    Wt[(size_t)(n0 + ty + i * 8) * Cv + k0 + tx] = f2b(s[tx][ty + i * 8]);
}

// ------ GEMM + fused attention dots: h2 = xb @ Wt^T; asrc/adst epilogue ----
// 256x128 tile, BK=64, 8 waves (4x2), 512 threads -> grid 6x40 = 240 blocks
// (~1/CU, single balanced round). Each 64-col wave covers exactly 1 head.
__global__ __launch_bounds__(512) void k_gemm_mfma(const unsigned short* __restrict__ A,
                                                   const unsigned short* __restrict__ Bt,
                                                   unsigned short* __restrict__ C,
                                                   const float* __restrict__ att_src,
                                                   const float* __restrict__ att_dst,
                                                   float* __restrict__ asrc,
                                                   float* __restrict__ adst) {
  __shared__ unsigned short As[256 * 64];
  __shared__ unsigned short Bs[128 * 64];
  const int t = threadIdx.x;
  const int w = t >> 6, l = t & 63;
  const int wr = w >> 1, wc = w & 1;          // 4 x 2 wave grid
  const int bm = blockIdx.y * 256, bn = blockIdx.x * 128;
  const int g = l >> 4, li = l & 15;
  f32x4 acc[4][4] = {};

  const int rs = t >> 3;              // staging row within 64-row issue (0..63)
  const int sl = (t & 7) ^ (rs & 7);  // pre-swizzled logical slot for source

  for (int k0 = 0; k0 < Cv; k0 += 64) {
#pragma unroll
    for (int i = 0; i < 4; ++i) {  // A: 4 issues x 64 rows
      const int r = i * 64 + rs;
      GLD16(A + (size_t)(bm + r) * Cv + k0 + sl * 8, &As[t * 8 + i * 4096]);
    }
#pragma unroll
    for (int i = 0; i < 2; ++i) {  // B: 2 issues x 64 rows
      const int r = i * 64 + rs;
      GLD16(Bt + (size_t)(bn + r) * Cv + k0 + sl * 8, &Bs[t * 8 + i * 4096]);
    }
    __syncthreads();  // drains vmcnt(0): LDS tiles ready for all waves
#pragma unroll
    for (int ks = 0; ks < 2; ++ks) {
      bf16x8 a[4], b[4];
#pragma unroll
      for (int mi = 0; mi < 4; ++mi) {
        const int row = wr * 64 + mi * 16 + li;
        const int slot = (ks * 4 + g) ^ (row & 7);
        a[mi] = *(const bf16x8*)&As[row * 64 + slot * 8];
      }
#pragma unroll
      for (int nj = 0; nj < 4; ++nj) {
        const int row = wc * 64 + nj * 16 + li;
        const int slot = (ks * 4 + g) ^ (row & 7);
        b[nj] = *(const bf16x8*)&Bs[row * 64 + slot * 8];
      }
#pragma unroll
      for (int mi = 0; mi < 4; ++mi)
#pragma unroll
        for (int nj = 0; nj < 4; ++nj)
          acc[mi][nj] = __builtin_amdgcn_mfma_f32_16x16x32_bf16(a[mi], b[nj], acc[mi][nj], 0, 0, 0);
    }
    __syncthreads();  // protect LDS before next stage
  }
  // C/D layout: col = lane&15, row = (lane>>4)*4 + reg (m89-verified)
#pragma unroll
  for (int mi = 0; mi < 4; ++mi) {
#pragma unroll
    for (int nj = 0; nj < 4; ++nj) {
      const int col = bn + wc * 64 + nj * 16 + li;
#pragma unroll
      for (int r4 = 0; r4 < 4; ++r4) {
        const int row = bm + wr * 64 + mi * 16 + g * 4 + r4;
        C[(size_t)row * HD + col] = f2b(acc[mi][nj][r4]);
      }
    }
  }
  // fused attention-dot epilogue: head covered by this wave's 64 cols
  {
    const int head = (bn >> 6) + wc;  // 2*blockIdx.x + wc
    float aS[4], aD[4];
#pragma unroll
    for (int nj = 0; nj < 4; ++nj) {
      aS[nj] = att_src[head * Dv + nj * 16 + li];
      aD[nj] = att_dst[head * Dv + nj * 16 + li];
    }
#pragma unroll
    for (int mi = 0; mi < 4; ++mi) {
#pragma unroll
      for (int r4 = 0; r4 < 4; ++r4) {
        float vs = 0.f, vd = 0.f;
#pragma unroll
        for (int nj = 0; nj < 4; ++nj) {
          const float hv = acc[mi][nj][r4];
          vs = fmaf(hv, aS[nj], vs);
          vd = fmaf(hv, aD[nj], vd);
        }
        vs += __shfl_xor(vs, 1); vd += __shfl_xor(vd, 1);
        vs += __shfl_xor(vs, 2); vd += __shfl_xor(vd, 2);
        vs += __shfl_xor(vs, 4); vd += __shfl_xor(vd, 4);
        vs += __shfl_xor(vs, 8); vd += __shfl_xor(vd, 8);
        const int row = bm + wr * 64 + mi * 16 + g * 4 + r4;
        if (li == 0 && row < Mv) {
          asrc[(size_t)row * Hv + head] = vs;
          adst[(size_t)row * Hv + head] = vd;
        }
      }
    }
  }
}

// ---------------- CSR build ------------------------------------------------
__global__ void k_count(const int* __restrict__ ei, int* __restrict__ counts) {
  int e = blockIdx.x * blockDim.x + threadIdx.x;
  if (e >= ETOT) return;
  int dst = (e < Ev) ? ei[Ev + e] : (e - Ev);
  atomicAdd(&counts[dst], 1);
}

__global__ __launch_bounds__(1024) void k_scan(const int* __restrict__ counts,
                                               int* __restrict__ offsets) {
  __shared__ int part[1024];
  const int t = threadIdx.x;
  const int chunk = 5;  // 1024*5 >= 5000
  int begin = t * chunk;
  int end = begin + chunk;
  if (end > Nv) end = Nv;
  if (begin > Nv) begin = Nv;
  int s = 0;
  for (int i = begin; i < end; ++i) s += counts[i];
  part[t] = s;
  __syncthreads();
  for (int off = 1; off < 1024; off <<= 1) {
    int v = (t >= off) ? part[t - off] : 0;
    __syncthreads();
    part[t] += v;
    __syncthreads();
  }
  int run = (t == 0) ? 0 : part[t - 1];
  for (int i = begin; i < end; ++i) {
    offsets[i] = run;
    run += counts[i];
  }
  if (t == 0) offsets[Nv] = ETOT;
}

__global__ void k_scatter(const int* __restrict__ ei, const int* __restrict__ offsets,
                          int* __restrict__ cursor, int* __restrict__ csr) {
  int e = blockIdx.x * blockDim.x + threadIdx.x;
  if (e >= ETOT) return;
  int dst = (e < Ev) ? ei[Ev + e] : (e - Ev);
  int pos = atomicAdd(&cursor[dst], 1);
  csr[offsets[dst] + pos] = e;
}

// ------- fused softmax + aggregation: block per (b, dim-half, n-pair) ------
// XCD pinning: xcd = blk&7 determines (b, half) -> each XCD's gather slice
// is 3.84 MB < 4 MB L2. 2 nodes per block keeps lanes at ushort4 (8 B).
// 192 threads: Phase A = 12 groups x 16 lanes = (2n x 6 heads); Phase B =
// 2 x 96 lanes, lane owns 4 dims of [half*384, half*384+384).
__global__ __launch_bounds__(192) void k_agg(const unsigned short* __restrict__ h2,
                                             const int* __restrict__ ei,
                                             const int* __restrict__ offsets,
                                             const int* __restrict__ csr,
                                             const float* __restrict__ asrc,
                                             const float* __restrict__ adst,
                                             const float* __restrict__ bias,
                                             float* __restrict__ out) {
  const int xcd = blockIdx.x & 7;
  const int idx = blockIdx.x >> 3;         // 0..1249
  const int b = xcd >> 2;
  const int half = (xcd >> 1) & 1;
  const int pair = (xcd & 1) * 1250 + idx; // 0..2499
  const int n0 = pair * 2;                 // block handles n0, n0+1
  const int t = threadIdx.x;
  __shared__ int s_src[2][DEGMAX];
  __shared__ float s_w[2][DEGMAX][6];
  __shared__ float s_inv[2][6];
  __shared__ int s_deg[2];
  if (t < 2) s_deg[t] = offsets[n0 + t + 1] - offsets[n0 + t];
  // stage both CSR lists (padded with row 0)
  {
    const int beg0 = offsets[n0], beg1 = offsets[n0 + 1], endv1 = offsets[n0 + 2];
    const int d0 = beg1 - beg0, d1 = endv1 - beg1;
    if (t < DEGMAX) {
      int sv = 0;
      if (t < d0) { int e = csr[beg0 + t]; sv = (e < Ev) ? ei[e] : (e - Ev); }
      s_src[0][t] = sv;
    }
    const int t2 = t - 64;
    if (t2 >= 0 && t2 < DEGMAX) {
      int sv = 0;
      if (t2 < d1) { int e = csr[beg1 + t2]; sv = (e < Ev) ? ei[e] : (e - Ev); }
      s_src[1][t2] = sv;
    }
  }
  __syncthreads();
  {
    const int grp = t >> 4;          // 0..11 = jn*6 + hl
    const int jj = t & 15;
    const int jn = grp / 6, hl = grp % 6;
    const int hh = half * 6 + hl;
    const int nn = n0 + jn;
    const int deg = s_deg[jn];
    const float adv = adst[((size_t)b * Nv + nn) * Hv + hh];
    float ps = 0.f;
#pragma unroll
    for (int k = 0; k < 8; ++k) {
      const int i = jj + k * 16;
      if (i < deg) {
        float v = asrc[((size_t)b * Nv + s_src[jn][i]) * Hv + hh] + adv;
        v = (v > 0.f) ? v : NEG * v;
        float ex = __expf(v);
        s_w[jn][i][hl] = ex;
        ps += ex;
      }
    }
    ps += __shfl_xor(ps, 1);
    ps += __shfl_xor(ps, 2);
    ps += __shfl_xor(ps, 4);
    ps += __shfl_xor(ps, 8);
    if (jj == 0) s_inv[jn][hl] = 1.0f / (ps + 1e-16f);
  }
  __syncthreads();
  // Phase B
  const int jn = t / 96;               // which node of the pair
  const int tl = t - jn * 96;          // 0..95
  const int hl = tl >> 4;              // local head 0..5
  const int deg = s_deg[jn];
  float acc0 = 0.f, acc1 = 0.f, acc2 = 0.f, acc3 = 0.f;
  const size_t hbase = (size_t)b * Nv * HD + half * 384 + tl * 4;
  ushort4 cA[4], cB[4];
#pragma unroll
  for (int k = 0; k < 4; ++k)
    cA[k] = *(const ushort4*)(h2 + hbase + (size_t)s_src[jn][k] * HD);
  for (int base = 0; base < deg; base += 8) {
#pragma unroll
    for (int k = 0; k < 4; ++k) {
      const int i = base + 4 + k;
      cB[k] = *(const ushort4*)(h2 + hbase + (size_t)s_src[jn][i < DEGMAX ? i : 0] * HD);
    }
#pragma unroll
    for (int k = 0; k < 4; ++k) {
      const int i = base + k;
      if (i < deg) {
        const float w = s_w[jn][i][hl];
        acc0 = fmaf(w, b2f(cA[k].x), acc0);
        acc1 = fmaf(w, b2f(cA[k].y), acc1);
        acc2 = fmaf(w, b2f(cA[k].z), acc2);
        acc3 = fmaf(w, b2f(cA[k].w), acc3);
      }
    }
#pragma unroll
    for (int k = 0; k < 4; ++k) {
      const int i = base + 8 + k;
      cA[k] = *(const ushort4*)(h2 + hbase + (size_t)s_src[jn][i < DEGMAX ? i : 0] * HD);
    }
#pragma unroll
    for (int k = 0; k < 4; ++k) {
      const int i = base + 4 + k;
      if (i < deg) {
        const float w = s_w[jn][i][hl];
        acc0 = fmaf(w, b2f(cB[k].x), acc0);
        acc1 = fmaf(w, b2f(cB[k].y), acc1);
        acc2 = fmaf(w, b2f(cB[k].z), acc2);
        acc3 = fmaf(w, b2f(cB[k].w), acc3);
      }
    }
  }
  const float invh = s_inv[jn][hl];
  const int od = half * 384 + tl * 4;
  float4 o;
  o.x = fmaf(acc0, invh, bias[od + 0]);
  o.y = fmaf(acc1, invh, bias[od + 1]);
  o.z = fmaf(acc2, invh, bias[od + 2]);
  o.w = fmaf(acc3, invh, bias[od + 3]);
  *(float4*)(out + ((size_t)b * Nv + n0 + jn) * HD + od) = o;
}

extern "C" void kernel_launch(void* const* d_in, const int* in_sizes, int n_in,
                              void* d_out, int out_size, void* d_ws, size_t ws_size,
                              hipStream_t stream) {
  const float* x = (const float*)d_in[0];
  const float* W = (const float*)d_in[1];
  const float* att_src = (const float*)d_in[2];
  const float* att_dst = (const float*)d_in[3];
  const float* bias = (const float*)d_in[4];
  const int* ei = (const int*)d_in[5];
  float* out = (float*)d_out;

  // workspace layout
  unsigned short* h2 = (unsigned short*)d_ws;            // MPAD*768 bf16
  unsigned short* xbf = h2 + (size_t)MPAD * HD;          // MPAD*768 bf16
  unsigned short* wt = xbf + (size_t)MPAD * HD;          // 768*768 bf16
  float* asrc = (float*)(wt + (size_t)HD * Cv);          // 120,000 f32
  float* adst = asrc + (size_t)Bv * Nv * Hv;             // 120,000 f32
  int* counts = (int*)(adst + (size_t)Bv * Nv * Hv);     // Nv
  int* cursor = counts + Nv;                             // Nv
  int* offsets = cursor + Nv;                            // Nv+1
  int* csr = offsets + Nv + 1;                           // ETOT

  hipMemsetAsync(counts, 0, sizeof(int) * 2 * Nv, stream);

  k_cvt_x<<<(int)(((size_t)MPAD * HD / 8 + 255) / 256), 256, 0, stream>>>(x, xbf);
  k_cvt_wt<<<dim3(HD / 32, Cv / 32), dim3(32, 8), 0, stream>>>(W, wt);
  k_gemm_mfma<<<dim3(HD / 128, MPAD / 256), 512, 0, stream>>>(xbf, wt, h2, att_src, att_dst, asrc, adst);
  k_count<<<(ETOT + 255) / 256, 256, 0, stream>>>(ei, counts);
  k_scan<<<1, 1024, 0, stream>>>(counts, offsets);
  k_scatter<<<(ETOT + 255) / 256, 256, 0, stream>>>(ei, offsets, cursor, csr);
  k_agg<<<Bv * Nv, 192, 0, stream>>>(h2, ei, offsets, csr, asrc, adst, bias, out);
}

// Round 10
// 142.115 us; speedup vs baseline: 1.0088x; 1.0088x over previous
//
#include <hip/hip_runtime.h>

#define Bv 2
#define Nv 5000
#define Cv 768
#define Hv 12
#define Dv 64
#define Ev 160000
#define ETOT (Ev + Nv)   // 165000 (edges + self loops)
#define HD 768
#define NEG 0.2f
#define Mv (Bv * Nv)     // 10000
#define MPAD 10240       // 40 * 256
#define DEGMAX 128       // max in-degree incl. self-loop; Poisson(33) tail -> safe
#define DEGPAD 136       // staging pad so prefetch can overread

typedef __bf16 bf16x8 __attribute__((ext_vector_type(8)));
typedef float f32x4 __attribute__((ext_vector_type(4)));

// direct-to-LDS 16B async copy
#define GLD16(gsrc, ldst)                                                      \
  __builtin_amdgcn_global_load_lds(                                            \
      (const __attribute__((address_space(1))) unsigned int*)(gsrc),           \
      (__attribute__((address_space(3))) unsigned int*)(ldst), 16, 0, 0)

// f32 -> bf16 round-to-nearest-even
__device__ __forceinline__ unsigned short f2b(float f) {
  unsigned u = __float_as_uint(f);
  return (unsigned short)((u + 0x7FFFu + ((u >> 16) & 1u)) >> 16);
}

// ---- merged prep: cvt_x (3840 blocks) | cvt_wt (576) | count (645) --------
#define NB_CVTX 3840   // MPAD*HD/8/256
#define NB_CVTW 576    // (768/32)*(768/32)
#define NB_CNT  645    // ceil(ETOT/256)
__global__ __launch_bounds__(256) void k_prep(const float* __restrict__ x,
                                              unsigned short* __restrict__ xb,
                                              const float* __restrict__ W,
                                              unsigned short* __restrict__ Wt,
                                              const int* __restrict__ ei,
                                              int* __restrict__ counts) {
  const int blk = blockIdx.x;
  const int t = threadIdx.x;
  if (blk < NB_CVTX) {
    size_t i = ((size_t)blk * 256 + t) * 8;
    unsigned short o[8];
    if (i < (size_t)Mv * Cv) {
      float4 v0 = *(const float4*)(x + i);
      float4 v1 = *(const float4*)(x + i + 4);
      o[0] = f2b(v0.x); o[1] = f2b(v0.y); o[2] = f2b(v0.z); o[3] = f2b(v0.w);
      o[4] = f2b(v1.x); o[5] = f2b(v1.y); o[6] = f2b(v1.z); o[7] = f2b(v1.w);
    } else {
      for (int j = 0; j < 8; ++j) o[j] = 0;
    }
    *(uint4*)(xb + i) = *(const uint4*)o;
  } else if (blk < NB_CVTX + NB_CVTW) {
    __shared__ float s[32][33];
    const int bw = blk - NB_CVTX;
    const int n0 = (bw % 24) * 32, k0 = (bw / 24) * 32;
    const int tx = t & 31, ty = t >> 5;  // 32 x 8
#pragma unroll
    for (int i = 0; i < 4; ++i)
      s[ty + i * 8][tx] = W[(size_t)(k0 + ty + i * 8) * HD + n0 + tx];
    __syncthreads();
#pragma unroll
    for (int i = 0; i < 4; ++i)
      Wt[(size_t)(n0 + ty + i * 8) * Cv + k0 + tx] = f2b(s[tx][ty + i * 8]);
  } else {
    const int e = (blk - NB_CVTX - NB_CVTW) * 256 + t;
    if (e < ETOT) {
      int dst = (e < Ev) ? ei[Ev + e] : (e - Ev);
      atomicAdd(&counts[dst], 1);
    }
  }
}

// ------ GEMM + fused attention dots: h2 = xb @ Wt^T; asrc/adst epilogue ----
// 256x128 tile, BK=64, 8 waves (4x2), 512 threads -> grid 6x40 = 240 blocks.
__global__ __launch_bounds__(512) void k_gemm_mfma(const unsigned short* __restrict__ A,
                                                   const unsigned short* __restrict__ Bt,
                                                   unsigned short* __restrict__ C,
                                                   const float* __restrict__ att_src,
                                                   const float* __restrict__ att_dst,
                                                   float* __restrict__ asrc,
                                                   float* __restrict__ adst) {
  __shared__ unsigned short As[256 * 64];
  __shared__ unsigned short Bs[128 * 64];
  const int t = threadIdx.x;
  const int w = t >> 6, l = t & 63;
  const int wr = w >> 1, wc = w & 1;          // 4 x 2 wave grid
  const int bm = blockIdx.y * 256, bn = blockIdx.x * 128;
  const int g = l >> 4, li = l & 15;
  f32x4 acc[4][4] = {};

  const int rs = t >> 3;              // staging row within 64-row issue (0..63)
  const int sl = (t & 7) ^ (rs & 7);  // pre-swizzled logical slot for source

  for (int k0 = 0; k0 < Cv; k0 += 64) {
#pragma unroll
    for (int i = 0; i < 4; ++i) {  // A: 4 issues x 64 rows
      const int r = i * 64 + rs;
      GLD16(A + (size_t)(bm + r) * Cv + k0 + sl * 8, &As[t * 8 + i * 4096]);
    }
#pragma unroll
    for (int i = 0; i < 2; ++i) {  // B: 2 issues x 64 rows
      const int r = i * 64 + rs;
      GLD16(Bt + (size_t)(bn + r) * Cv + k0 + sl * 8, &Bs[t * 8 + i * 4096]);
    }
    __syncthreads();  // drains vmcnt(0): LDS tiles ready for all waves
#pragma unroll
    for (int ks = 0; ks < 2; ++ks) {
      bf16x8 a[4], b[4];
#pragma unroll
      for (int mi = 0; mi < 4; ++mi) {
        const int row = wr * 64 + mi * 16 + li;
        const int slot = (ks * 4 + g) ^ (row & 7);
        a[mi] = *(const bf16x8*)&As[row * 64 + slot * 8];
      }
#pragma unroll
      for (int nj = 0; nj < 4; ++nj) {
        const int row = wc * 64 + nj * 16 + li;
        const int slot = (ks * 4 + g) ^ (row & 7);
        b[nj] = *(const bf16x8*)&Bs[row * 64 + slot * 8];
      }
#pragma unroll
      for (int mi = 0; mi < 4; ++mi)
#pragma unroll
        for (int nj = 0; nj < 4; ++nj)
          acc[mi][nj] = __builtin_amdgcn_mfma_f32_16x16x32_bf16(a[mi], b[nj], acc[mi][nj], 0, 0, 0);
    }
    __syncthreads();  // protect LDS before next stage
  }
  // C/D layout: col = lane&15, row = (lane>>4)*4 + reg (m89-verified)
#pragma unroll
  for (int mi = 0; mi < 4; ++mi) {
#pragma unroll
    for (int nj = 0; nj < 4; ++nj) {
      const int col = bn + wc * 64 + nj * 16 + li;
#pragma unroll
      for (int r4 = 0; r4 < 4; ++r4) {
        const int row = bm + wr * 64 + mi * 16 + g * 4 + r4;
        C[(size_t)row * HD + col] = f2b(acc[mi][nj][r4]);
      }
    }
  }
  // fused attention-dot epilogue: head covered by this wave's 64 cols
  {
    const int head = (bn >> 6) + wc;  // 2*blockIdx.x + wc
    float aS[4], aD[4];
#pragma unroll
    for (int nj = 0; nj < 4; ++nj) {
      aS[nj] = att_src[head * Dv + nj * 16 + li];
      aD[nj] = att_dst[head * Dv + nj * 16 + li];
    }
#pragma unroll
    for (int mi = 0; mi < 4; ++mi) {
#pragma unroll
      for (int r4 = 0; r4 < 4; ++r4) {
        float vs = 0.f, vd = 0.f;
#pragma unroll
        for (int nj = 0; nj < 4; ++nj) {
          const float hv = acc[mi][nj][r4];
          vs = fmaf(hv, aS[nj], vs);
          vd = fmaf(hv, aD[nj], vd);
        }
        vs += __shfl_xor(vs, 1); vd += __shfl_xor(vd, 1);
        vs += __shfl_xor(vs, 2); vd += __shfl_xor(vd, 2);
        vs += __shfl_xor(vs, 4); vd += __shfl_xor(vd, 4);
        vs += __shfl_xor(vs, 8); vd += __shfl_xor(vd, 8);
        const int row = bm + wr * 64 + mi * 16 + g * 4 + r4;
        if (li == 0 && row < Mv) {
          asrc[(size_t)row * Hv + head] = vs;
          adst[(size_t)row * Hv + head] = vd;
        }
      }
    }
  }
}

// ---------------- CSR scan + scatter ---------------------------------------
__global__ __launch_bounds__(1024) void k_scan(const int* __restrict__ counts,
                                               int* __restrict__ offsets) {
  __shared__ int part[1024];
  const int t = threadIdx.x;
  const int chunk = 5;  // 1024*5 >= 5000
  int begin = t * chunk;
  int end = begin + chunk;
  if (end > Nv) end = Nv;
  if (begin > Nv) begin = Nv;
  int s = 0;
  for (int i = begin; i < end; ++i) s += counts[i];
  part[t] = s;
  __syncthreads();
  for (int off = 1; off < 1024; off <<= 1) {
    int v = (t >= off) ? part[t - off] : 0;
    __syncthreads();
    part[t] += v;
    __syncthreads();
  }
  int run = (t == 0) ? 0 : part[t - 1];
  for (int i = begin; i < end; ++i) {
    offsets[i] = run;
    run += counts[i];
  }
  if (t == 0) offsets[Nv] = ETOT;
}

__global__ void k_scatter(const int* __restrict__ ei, const int* __restrict__ offsets,
                          int* __restrict__ cursor, int* __restrict__ csr) {
  int e = blockIdx.x * blockDim.x + threadIdx.x;
  if (e >= ETOT) return;
  int dst = (e < Ev) ? ei[Ev + e] : (e - Ev);
  int pos = atomicAdd(&cursor[dst], 1);
  csr[offsets[dst] + pos] = e;
}

// ------- fused softmax + aggregation: block per (b, n-pair) ----------------
// XCD pinned on batch only (xcd>>2 = b). 192 threads = 2 nodes x 96 lanes,
// lane owns 8 dims via one uint4 (16B) per edge -> half the loads of R8.
// s_w transposed [node][head][128] and ZERO-PADDED past deg: inner loop has
// no guards; weights read 4-at-a-time (ds_read_b128). bf16->f32 = 1 op/elem.
#define EDGE_FMA(c, wv)                                            \
  {                                                                \
    acc[0] = fmaf(wv, __uint_as_float((c).x << 16), acc[0]);       \
    acc[1] = fmaf(wv, __uint_as_float((c).x & 0xFFFF0000u), acc[1]); \
    acc[2] = fmaf(wv, __uint_as_float((c).y << 16), acc[2]);       \
    acc[3] = fmaf(wv, __uint_as_float((c).y & 0xFFFF0000u), acc[3]); \
    acc[4] = fmaf(wv, __uint_as_float((c).z << 16), acc[4]);       \
    acc[5] = fmaf(wv, __uint_as_float((c).z & 0xFFFF0000u), acc[5]); \
    acc[6] = fmaf(wv, __uint_as_float((c).w << 16), acc[6]);       \
    acc[7] = fmaf(wv, __uint_as_float((c).w & 0xFFFF0000u), acc[7]); \
  }

__global__ __launch_bounds__(192) void k_agg(const unsigned short* __restrict__ h2,
                                             const int* __restrict__ ei,
                                             const int* __restrict__ offsets,
                                             const int* __restrict__ csr,
                                             const float* __restrict__ asrc,
                                             const float* __restrict__ adst,
                                             const float* __restrict__ bias,
                                             float* __restrict__ out) {
  const int xcd = blockIdx.x & 7;
  const int idx = blockIdx.x >> 3;        // 0..624
  const int b = xcd >> 2;
  const int pair = (xcd & 3) * 625 + idx; // 0..2499
  const int n0 = pair * 2;                // block handles n0, n0+1
  const int t = threadIdx.x;
  __shared__ int s_src[2][DEGPAD];
  __shared__ float s_w[2][Hv][DEGMAX];
  __shared__ float s_inv[2][Hv];
  __shared__ int s_deg[2];
  const int beg0 = offsets[n0], beg1 = offsets[n0 + 1], end1 = offsets[n0 + 2];
  const int d0 = beg1 - beg0, d1 = end1 - beg1;  // <= DEGMAX
  if (t < 2) s_deg[t] = t ? d1 : d0;
  for (int i = t; i < 2 * DEGPAD; i += 192) {
    const int jn = i >= DEGPAD;
    const int ii = i - jn * DEGPAD;
    const int dd = jn ? d1 : d0;
    const int bb = jn ? beg1 : beg0;
    int sv = 0;
    if (ii < dd) { int e = csr[bb + ii]; sv = (e < Ev) ? ei[e] : (e - Ev); }
    s_src[jn][ii] = sv;  // pad with row 0 (safe to load, weight = 0)
  }
  __syncthreads();
  // Phase A: 24 groups x 8 lanes = (node, head); writes all 128 w (0-padded)
  {
    const int grp = t >> 3, jj = t & 7;
    const int jn = grp / Hv, hh = grp % Hv;
    const int deg = jn ? d1 : d0;
    const float adv = adst[((size_t)b * Nv + n0 + jn) * Hv + hh];
    float ps = 0.f;
#pragma unroll
    for (int k = 0; k < 16; ++k) {
      const int i = jj + k * 8;
      float ex = 0.f;
      if (i < deg) {
        float v = asrc[((size_t)b * Nv + s_src[jn][i]) * Hv + hh] + adv;
        v = (v > 0.f) ? v : NEG * v;
        ex = __expf(v);
      }
      s_w[jn][hh][i] = ex;
      ps += ex;
    }
    ps += __shfl_xor(ps, 1);
    ps += __shfl_xor(ps, 2);
    ps += __shfl_xor(ps, 4);
    if (jj == 0) s_inv[jn][hh] = 1.0f / (ps + 1e-16f);
  }
  __syncthreads();
  // Phase B: node jn, lane tl owns dims [8tl, 8tl+8); no guards (0-padded w)
  const int jn = t >= 96;
  const int tl = t - jn * 96;
  const int hl = tl >> 3;  // head
  const int degp = ((jn ? d1 : d0) + 7) & ~7;
  float acc[8] = {};
  const unsigned short* hrow = h2 + (size_t)b * Nv * HD + tl * 8;
  uint4 cA[4], cB[4];
#pragma unroll
  for (int k = 0; k < 4; ++k)
    cA[k] = *(const uint4*)(hrow + (size_t)s_src[jn][k] * HD);
  for (int base = 0; base < degp; base += 8) {
#pragma unroll
    for (int k = 0; k < 4; ++k)
      cB[k] = *(const uint4*)(hrow + (size_t)s_src[jn][base + 4 + k] * HD);
    {
      const f32x4 w4 = *(const f32x4*)&s_w[jn][hl][base];
      EDGE_FMA(cA[0], w4[0]); EDGE_FMA(cA[1], w4[1]);
      EDGE_FMA(cA[2], w4[2]); EDGE_FMA(cA[3], w4[3]);
    }
#pragma unroll
    for (int k = 0; k < 4; ++k)
      cA[k] = *(const uint4*)(hrow + (size_t)s_src[jn][base + 8 + k] * HD);
    {
      const f32x4 w4 = *(const f32x4*)&s_w[jn][hl][base + 4];
      EDGE_FMA(cB[0], w4[0]); EDGE_FMA(cB[1], w4[1]);
      EDGE_FMA(cB[2], w4[2]); EDGE_FMA(cB[3], w4[3]);
    }
  }
  const float invh = s_inv[jn][hl];
  const int od = tl * 8;
  float4 o0, o1;
  o0.x = fmaf(acc[0], invh, bias[od + 0]);
  o0.y = fmaf(acc[1], invh, bias[od + 1]);
  o0.z = fmaf(acc[2], invh, bias[od + 2]);
  o0.w = fmaf(acc[3], invh, bias[od + 3]);
  o1.x = fmaf(acc[4], invh, bias[od + 4]);
  o1.y = fmaf(acc[5], invh, bias[od + 5]);
  o1.z = fmaf(acc[6], invh, bias[od + 6]);
  o1.w = fmaf(acc[7], invh, bias[od + 7]);
  float* op = out + ((size_t)b * Nv + n0 + jn) * HD + od;
  *(float4*)op = o0;
  *(float4*)(op + 4) = o1;
}

extern "C" void kernel_launch(void* const* d_in, const int* in_sizes, int n_in,
                              void* d_out, int out_size, void* d_ws, size_t ws_size,
                              hipStream_t stream) {
  const float* x = (const float*)d_in[0];
  const float* W = (const float*)d_in[1];
  const float* att_src = (const float*)d_in[2];
  const float* att_dst = (const float*)d_in[3];
  const float* bias = (const float*)d_in[4];
  const int* ei = (const int*)d_in[5];
  float* out = (float*)d_out;

  // workspace layout
  unsigned short* h2 = (unsigned short*)d_ws;            // MPAD*768 bf16
  unsigned short* xbf = h2 + (size_t)MPAD * HD;          // MPAD*768 bf16
  unsigned short* wt = xbf + (size_t)MPAD * HD;          // 768*768 bf16
  float* asrc = (float*)(wt + (size_t)HD * Cv);          // 120,000 f32
  float* adst = asrc + (size_t)Bv * Nv * Hv;             // 120,000 f32
  int* counts = (int*)(adst + (size_t)Bv * Nv * Hv);     // Nv
  int* cursor = counts + Nv;                             // Nv
  int* offsets = cursor + Nv;                            // Nv+1
  int* csr = offsets + Nv + 1;                           // ETOT

  hipMemsetAsync(counts, 0, sizeof(int) * 2 * Nv, stream);

  k_prep<<<NB_CVTX + NB_CVTW + NB_CNT, 256, 0, stream>>>(x, xbf, W, wt, ei, counts);
  k_gemm_mfma<<<dim3(HD / 128, MPAD / 256), 512, 0, stream>>>(xbf, wt, h2, att_src, att_dst, asrc, adst);
  k_scan<<<1, 1024, 0, stream>>>(counts, offsets);
  k_scatter<<<(ETOT + 255) / 256, 256, 0, stream>>>(ei, offsets, cursor, csr);
  k_agg<<<Bv * Nv / 2, 192, 0, stream>>>(h2, ei, offsets, csr, asrc, adst, bias, out);
}

// Round 11
// 136.028 us; speedup vs baseline: 1.0540x; 1.0447x over previous
//
#include <hip/hip_runtime.h>

#define Bv 2
#define Nv 5000
#define Cv 768
#define Hv 12
#define Dv 64
#define Ev 160000
#define ETOT (Ev + Nv)   // 165000 (edges + self loops)
#define HD 768
#define NEG 0.2f
#define Mv (Bv * Nv)     // 10000
#define MPAD 10240       // 40 * 256
#define DEGMAX 128       // max in-degree incl. self-loop; Poisson(33) tail -> safe
#define DEGPAD 136       // staging pad so prefetch can overread
#define DEGW 132         // s_w edge stride: 4*33 keeps 16B align, spreads banks

typedef __bf16 bf16x8 __attribute__((ext_vector_type(8)));
typedef float f32x4 __attribute__((ext_vector_type(4)));

// direct-to-LDS 16B async copy
#define GLD16(gsrc, ldst)                                                      \
  __builtin_amdgcn_global_load_lds(                                            \
      (const __attribute__((address_space(1))) unsigned int*)(gsrc),           \
      (__attribute__((address_space(3))) unsigned int*)(ldst), 16, 0, 0)

// f32 -> bf16 round-to-nearest-even
__device__ __forceinline__ unsigned short f2b(float f) {
  unsigned u = __float_as_uint(f);
  return (unsigned short)((u + 0x7FFFu + ((u >> 16) & 1u)) >> 16);
}

// ---- merged prep: cvt_x (3840 blocks) | cvt_wt (576) | count (645) --------
#define NB_CVTX 3840   // MPAD*HD/8/256
#define NB_CVTW 576    // (768/32)*(768/32)
#define NB_CNT  645    // ceil(ETOT/256)
__global__ __launch_bounds__(256) void k_prep(const float* __restrict__ x,
                                              unsigned short* __restrict__ xb,
                                              const float* __restrict__ W,
                                              unsigned short* __restrict__ Wt,
                                              const int* __restrict__ ei,
                                              int* __restrict__ counts) {
  const int blk = blockIdx.x;
  const int t = threadIdx.x;
  if (blk < NB_CVTX) {
    size_t i = ((size_t)blk * 256 + t) * 8;
    unsigned short o[8];
    if (i < (size_t)Mv * Cv) {
      float4 v0 = *(const float4*)(x + i);
      float4 v1 = *(const float4*)(x + i + 4);
      o[0] = f2b(v0.x); o[1] = f2b(v0.y); o[2] = f2b(v0.z); o[3] = f2b(v0.w);
      o[4] = f2b(v1.x); o[5] = f2b(v1.y); o[6] = f2b(v1.z); o[7] = f2b(v1.w);
    } else {
      for (int j = 0; j < 8; ++j) o[j] = 0;
    }
    *(uint4*)(xb + i) = *(const uint4*)o;
  } else if (blk < NB_CVTX + NB_CVTW) {
    __shared__ float s[32][33];
    const int bw = blk - NB_CVTX;
    const int n0 = (bw % 24) * 32, k0 = (bw / 24) * 32;
    const int tx = t & 31, ty = t >> 5;  // 32 x 8
#pragma unroll
    for (int i = 0; i < 4; ++i)
      s[ty + i * 8][tx] = W[(size_t)(k0 + ty + i * 8) * HD + n0 + tx];
    __syncthreads();
#pragma unroll
    for (int i = 0; i < 4; ++i)
      Wt[(size_t)(n0 + ty + i * 8) * Cv + k0 + tx] = f2b(s[tx][ty + i * 8]);
  } else {
    const int e = (blk - NB_CVTX - NB_CVTW) * 256 + t;
    if (e < ETOT) {
      int dst = (e < Ev) ? ei[Ev + e] : (e - Ev);
      atomicAdd(&counts[dst], 1);
    }
  }
}

// ------ GEMM + fused attention dots: h2 = xb @ Wt^T; asrc/adst epilogue ----
// 256x128 tile, BK=64, 8 waves (4x2), 512 threads, 1D grid 240.
// XCD swizzle: all 6 N-tiles of one M-block land on the same XCD
// (xcd = l&7 round-robin heuristic) -> A-tile read once from HBM, then L2.
__global__ __launch_bounds__(512) void k_gemm_mfma(const unsigned short* __restrict__ A,
                                                   const unsigned short* __restrict__ Bt,
                                                   unsigned short* __restrict__ C,
                                                   const float* __restrict__ att_src,
                                                   const float* __restrict__ att_dst,
                                                   float* __restrict__ asrc,
                                                   float* __restrict__ adst) {
  __shared__ unsigned short As[256 * 64];
  __shared__ unsigned short Bs[128 * 64];
  const int l0 = blockIdx.x;
  const int xcd = l0 & 7, j = l0 >> 3;        // j < 30
  const int bm = (xcd + 8 * (j / 6)) * 256;   // M-block pinned to xcd
  const int bn = (j % 6) * 128;
  const int t = threadIdx.x;
  const int w = t >> 6, l = t & 63;
  const int wr = w >> 1, wc = w & 1;          // 4 x 2 wave grid
  const int g = l >> 4, li = l & 15;
  f32x4 acc[4][4] = {};

  const int rs = t >> 3;              // staging row within 64-row issue (0..63)
  const int sl = (t & 7) ^ (rs & 7);  // pre-swizzled logical slot for source

  for (int k0 = 0; k0 < Cv; k0 += 64) {
#pragma unroll
    for (int i = 0; i < 4; ++i) {  // A: 4 issues x 64 rows
      const int r = i * 64 + rs;
      GLD16(A + (size_t)(bm + r) * Cv + k0 + sl * 8, &As[t * 8 + i * 4096]);
    }
#pragma unroll
    for (int i = 0; i < 2; ++i) {  // B: 2 issues x 64 rows
      const int r = i * 64 + rs;
      GLD16(Bt + (size_t)(bn + r) * Cv + k0 + sl * 8, &Bs[t * 8 + i * 4096]);
    }
    __syncthreads();  // drains vmcnt(0): LDS tiles ready for all waves
#pragma unroll
    for (int ks = 0; ks < 2; ++ks) {
      bf16x8 a[4], b[4];
#pragma unroll
      for (int mi = 0; mi < 4; ++mi) {
        const int row = wr * 64 + mi * 16 + li;
        const int slot = (ks * 4 + g) ^ (row & 7);
        a[mi] = *(const bf16x8*)&As[row * 64 + slot * 8];
      }
#pragma unroll
      for (int nj = 0; nj < 4; ++nj) {
        const int row = wc * 64 + nj * 16 + li;
        const int slot = (ks * 4 + g) ^ (row & 7);
        b[nj] = *(const bf16x8*)&Bs[row * 64 + slot * 8];
      }
#pragma unroll
      for (int mi = 0; mi < 4; ++mi)
#pragma unroll
        for (int nj = 0; nj < 4; ++nj)
          acc[mi][nj] = __builtin_amdgcn_mfma_f32_16x16x32_bf16(a[mi], b[nj], acc[mi][nj], 0, 0, 0);
    }
    __syncthreads();  // protect LDS before next stage
  }
  // C/D layout: col = lane&15, row = (lane>>4)*4 + reg (m89-verified)
#pragma unroll
  for (int mi = 0; mi < 4; ++mi) {
#pragma unroll
    for (int nj = 0; nj < 4; ++nj) {
      const int col = bn + wc * 64 + nj * 16 + li;
#pragma unroll
      for (int r4 = 0; r4 < 4; ++r4) {
        const int row = bm + wr * 64 + mi * 16 + g * 4 + r4;
        C[(size_t)row * HD + col] = f2b(acc[mi][nj][r4]);
      }
    }
  }
  // fused attention-dot epilogue: head covered by this wave's 64 cols
  {
    const int head = (bn >> 6) + wc;
    float aS[4], aD[4];
#pragma unroll
    for (int nj = 0; nj < 4; ++nj) {
      aS[nj] = att_src[head * Dv + nj * 16 + li];
      aD[nj] = att_dst[head * Dv + nj * 16 + li];
    }
#pragma unroll
    for (int mi = 0; mi < 4; ++mi) {
#pragma unroll
      for (int r4 = 0; r4 < 4; ++r4) {
        float vs = 0.f, vd = 0.f;
#pragma unroll
        for (int nj = 0; nj < 4; ++nj) {
          const float hv = acc[mi][nj][r4];
          vs = fmaf(hv, aS[nj], vs);
          vd = fmaf(hv, aD[nj], vd);
        }
        vs += __shfl_xor(vs, 1); vd += __shfl_xor(vd, 1);
        vs += __shfl_xor(vs, 2); vd += __shfl_xor(vd, 2);
        vs += __shfl_xor(vs, 4); vd += __shfl_xor(vd, 4);
        vs += __shfl_xor(vs, 8); vd += __shfl_xor(vd, 8);
        const int row = bm + wr * 64 + mi * 16 + g * 4 + r4;
        if (li == 0 && row < Mv) {
          asrc[(size_t)row * Hv + head] = vs;
          adst[(size_t)row * Hv + head] = vd;
        }
      }
    }
  }
}

// ---------------- CSR scan + scatter ---------------------------------------
__global__ __launch_bounds__(1024) void k_scan(const int* __restrict__ counts,
                                               int* __restrict__ offsets) {
  __shared__ int part[1024];
  const int t = threadIdx.x;
  const int chunk = 5;  // 1024*5 >= 5000
  int begin = t * chunk;
  int end = begin + chunk;
  if (end > Nv) end = Nv;
  if (begin > Nv) begin = Nv;
  int s = 0;
  for (int i = begin; i < end; ++i) s += counts[i];
  part[t] = s;
  __syncthreads();
  for (int off = 1; off < 1024; off <<= 1) {
    int v = (t >= off) ? part[t - off] : 0;
    __syncthreads();
    part[t] += v;
    __syncthreads();
  }
  int run = (t == 0) ? 0 : part[t - 1];
  for (int i = begin; i < end; ++i) {
    offsets[i] = run;
    run += counts[i];
  }
  if (t == 0) offsets[Nv] = ETOT;
}

__global__ void k_scatter(const int* __restrict__ ei, const int* __restrict__ offsets,
                          int* __restrict__ cursor, int* __restrict__ csr) {
  int e = blockIdx.x * blockDim.x + threadIdx.x;
  if (e >= ETOT) return;
  int dst = (e < Ev) ? ei[Ev + e] : (e - Ev);
  int pos = atomicAdd(&cursor[dst], 1);
  csr[offsets[dst] + pos] = e;
}

// ------- fused softmax + aggregation: block per (b, n-pair) ----------------
// XCD pinned on batch (xcd>>2 = b). 192 threads.
// Phase A: thread = (node jn, head-quad q, slot): ONE f32x4 asrc load serves
// 4 heads (4x fewer L2 requests); loop slot-strided (~1-2 real iters);
// leaky = fmax(v, 0.2v); f32x4 shuffle-reduce over 32 slots.
// s_w[2][12][DEGW=132]: 16B-aligned rows, heads spread across banks (2-way max).
// Phase B: 2 nodes x 96 lanes, lane owns 8 dims (uint4/edge), zero-padded
// weights -> no guards, 2-chunk prefetch pipeline.
#define EDGE_FMA(c, wv)                                              \
  {                                                                  \
    acc[0] = fmaf(wv, __uint_as_float((c).x << 16), acc[0]);         \
    acc[1] = fmaf(wv, __uint_as_float((c).x & 0xFFFF0000u), acc[1]); \
    acc[2] = fmaf(wv, __uint_as_float((c).y << 16), acc[2]);         \
    acc[3] = fmaf(wv, __uint_as_float((c).y & 0xFFFF0000u), acc[3]); \
    acc[4] = fmaf(wv, __uint_as_float((c).z << 16), acc[4]);         \
    acc[5] = fmaf(wv, __uint_as_float((c).z & 0xFFFF0000u), acc[5]); \
    acc[6] = fmaf(wv, __uint_as_float((c).w << 16), acc[6]);         \
    acc[7] = fmaf(wv, __uint_as_float((c).w & 0xFFFF0000u), acc[7]); \
  }

__global__ __launch_bounds__(192) void k_agg(const unsigned short* __restrict__ h2,
                                             const int* __restrict__ ei,
                                             const int* __restrict__ offsets,
                                             const int* __restrict__ csr,
                                             const float* __restrict__ asrc,
                                             const float* __restrict__ adst,
                                             const float* __restrict__ bias,
                                             float* __restrict__ out) {
  const int xcd = blockIdx.x & 7;
  const int idx = blockIdx.x >> 3;        // 0..624
  const int b = xcd >> 2;
  const int pair = (xcd & 3) * 625 + idx; // 0..2499
  const int n0 = pair * 2;                // block handles n0, n0+1
  const int t = threadIdx.x;
  __shared__ int s_src[2][DEGPAD];
  __shared__ float s_w[2][Hv][DEGW];
  __shared__ float s_inv[2][16];
  const int beg0 = offsets[n0], beg1 = offsets[n0 + 1], end1 = offsets[n0 + 2];
  const int d0 = beg1 - beg0, d1 = end1 - beg1;  // <= DEGMAX
  for (int i = t; i < 2 * DEGPAD; i += 192) {
    const int jn = i >= DEGPAD;
    const int ii = i - jn * DEGPAD;
    const int dd = jn ? d1 : d0;
    const int bb = jn ? beg1 : beg0;
    int sv = 0;
    if (ii < dd) { int e = csr[bb + ii]; sv = (e < Ev) ? ei[e] : (e - Ev); }
    s_src[jn][ii] = sv;  // pad with row 0 (safe to load, weight = 0)
  }
  __syncthreads();
  // Phase A
  {
    const int jn = t / 96, rq = t % 96;
    const int q = rq >> 5, slot = rq & 31;   // q = head quad (0..2)
    const int deg = jn ? d1 : d0;
    const int degp = (deg + 7) & ~7;
    const f32x4 adv4 = *(const f32x4*)&adst[((size_t)b * Nv + n0 + jn) * Hv + q * 4];
    f32x4 ps = {0.f, 0.f, 0.f, 0.f};
    for (int i = slot; i < deg; i += 32) {
      const int src = s_src[jn][i];
      const f32x4 as4 = *(const f32x4*)&asrc[((size_t)b * Nv + src) * Hv + q * 4];
#pragma unroll
      for (int jq = 0; jq < 4; ++jq) {
        float v = as4[jq] + adv4[jq];
        v = fmaxf(v, NEG * v);      // leaky_relu
        float ex = __expf(v);
        s_w[jn][q * 4 + jq][i] = ex;
        ps[jq] += ex;
      }
    }
    // zero-pad weights up to degp so Phase B needs no guards
    for (int i = deg + slot; i < degp; i += 32) {
#pragma unroll
      for (int jq = 0; jq < 4; ++jq) s_w[jn][q * 4 + jq][i] = 0.f;
    }
#pragma unroll
    for (int jq = 0; jq < 4; ++jq) {
      ps[jq] += __shfl_xor(ps[jq], 1);
      ps[jq] += __shfl_xor(ps[jq], 2);
      ps[jq] += __shfl_xor(ps[jq], 4);
      ps[jq] += __shfl_xor(ps[jq], 8);
      ps[jq] += __shfl_xor(ps[jq], 16);
    }
    if (slot == 0) {
      f32x4 inv;
#pragma unroll
      for (int jq = 0; jq < 4; ++jq) inv[jq] = 1.0f / (ps[jq] + 1e-16f);
      *(f32x4*)&s_inv[jn][q * 4] = inv;
    }
  }
  __syncthreads();
  // Phase B: node jn, lane tl owns dims [8tl, 8tl+8); no guards (0-padded w)
  const int jn = t >= 96;
  const int tl = t - jn * 96;
  const int hl = tl >> 3;  // head
  const int degp = ((jn ? d1 : d0) + 7) & ~7;
  float acc[8] = {};
  const unsigned short* hrow = h2 + (size_t)b * Nv * HD + tl * 8;
  uint4 cA[4], cB[4];
#pragma unroll
  for (int k = 0; k < 4; ++k)
    cA[k] = *(const uint4*)(hrow + (size_t)s_src[jn][k] * HD);
  for (int base = 0; base < degp; base += 8) {
#pragma unroll
    for (int k = 0; k < 4; ++k)
      cB[k] = *(const uint4*)(hrow + (size_t)s_src[jn][base + 4 + k] * HD);
    {
      const f32x4 w4 = *(const f32x4*)&s_w[jn][hl][base];
      EDGE_FMA(cA[0], w4[0]); EDGE_FMA(cA[1], w4[1]);
      EDGE_FMA(cA[2], w4[2]); EDGE_FMA(cA[3], w4[3]);
    }
#pragma unroll
    for (int k = 0; k < 4; ++k)
      cA[k] = *(const uint4*)(hrow + (size_t)s_src[jn][base + 8 + k] * HD);
    {
      const f32x4 w4 = *(const f32x4*)&s_w[jn][hl][base + 4];
      EDGE_FMA(cB[0], w4[0]); EDGE_FMA(cB[1], w4[1]);
      EDGE_FMA(cB[2], w4[2]); EDGE_FMA(cB[3], w4[3]);
    }
  }
  const float invh = s_inv[jn][hl];
  const int od = tl * 8;
  float4 o0, o1;
  o0.x = fmaf(acc[0], invh, bias[od + 0]);
  o0.y = fmaf(acc[1], invh, bias[od + 1]);
  o0.z = fmaf(acc[2], invh, bias[od + 2]);
  o0.w = fmaf(acc[3], invh, bias[od + 3]);
  o1.x = fmaf(acc[4], invh, bias[od + 4]);
  o1.y = fmaf(acc[5], invh, bias[od + 5]);
  o1.z = fmaf(acc[6], invh, bias[od + 6]);
  o1.w = fmaf(acc[7], invh, bias[od + 7]);
  float* op = out + ((size_t)b * Nv + n0 + jn) * HD + od;
  *(float4*)op = o0;
  *(float4*)(op + 4) = o1;
}

extern "C" void kernel_launch(void* const* d_in, const int* in_sizes, int n_in,
                              void* d_out, int out_size, void* d_ws, size_t ws_size,
                              hipStream_t stream) {
  const float* x = (const float*)d_in[0];
  const float* W = (const float*)d_in[1];
  const float* att_src = (const float*)d_in[2];
  const float* att_dst = (const float*)d_in[3];
  const float* bias = (const float*)d_in[4];
  const int* ei = (const int*)d_in[5];
  float* out = (float*)d_out;

  // workspace layout
  unsigned short* h2 = (unsigned short*)d_ws;            // MPAD*768 bf16
  unsigned short* xbf = h2 + (size_t)MPAD * HD;          // MPAD*768 bf16
  unsigned short* wt = xbf + (size_t)MPAD * HD;          // 768*768 bf16
  float* asrc = (float*)(wt + (size_t)HD * Cv);          // 120,000 f32
  float* adst = asrc + (size_t)Bv * Nv * Hv;             // 120,000 f32
  int* counts = (int*)(adst + (size_t)Bv * Nv * Hv);     // Nv
  int* cursor = counts + Nv;                             // Nv
  int* offsets = cursor + Nv;                            // Nv+1
  int* csr = offsets + Nv + 1;                           // ETOT

  hipMemsetAsync(counts, 0, sizeof(int) * 2 * Nv, stream);

  k_prep<<<NB_CVTX + NB_CVTW + NB_CNT, 256, 0, stream>>>(x, xbf, W, wt, ei, counts);
  k_gemm_mfma<<<240, 512, 0, stream>>>(xbf, wt, h2, att_src, att_dst, asrc, adst);
  k_scan<<<1, 1024, 0, stream>>>(counts, offsets);
  k_scatter<<<(ETOT + 255) / 256, 256, 0, stream>>>(ei, offsets, cursor, csr);
  k_agg<<<Bv * Nv / 2, 192, 0, stream>>>(h2, ei, offsets, csr, asrc, adst, bias, out);
}

// Round 12
// 134.938 us; speedup vs baseline: 1.0625x; 1.0081x over previous
//
#include <hip/hip_runtime.h>

#define Bv 2
#define Nv 5000
#define Cv 768
#define Hv 12
#define Dv 64
#define Ev 160000
#define ETOT (Ev + Nv)   // 165000 (edges + self loops)
#define HD 768
#define NEG 0.2f
#define Mv (Bv * Nv)     // 10000
#define MPAD 10240       // 40 * 256
#define DEGMAX 128       // max in-degree incl. self-loop; Poisson(33) tail -> safe
#define DEGPAD 136       // staging pad so prefetch can overread
#define DEGW 132         // s_w edge stride: 4*33 keeps 16B align, spreads banks

typedef __bf16 bf16x8 __attribute__((ext_vector_type(8)));
typedef float f32x4 __attribute__((ext_vector_type(4)));

// direct-to-LDS 16B async copy
#define GLD16(gsrc, ldst)                                                      \
  __builtin_amdgcn_global_load_lds(                                            \
      (const __attribute__((address_space(1))) unsigned int*)(gsrc),           \
      (__attribute__((address_space(3))) unsigned int*)(ldst), 16, 0, 0)

// f32 -> bf16 round-to-nearest-even
__device__ __forceinline__ unsigned short f2b(float f) {
  unsigned u = __float_as_uint(f);
  return (unsigned short)((u + 0x7FFFu + ((u >> 16) & 1u)) >> 16);
}

// ---- merged prep: cvt_x (3840 blocks) | cvt_wt (576) | count (645) --------
#define NB_CVTX 3840   // MPAD*HD/8/256
#define NB_CVTW 576    // (768/32)*(768/32)
#define NB_CNT  645    // ceil(ETOT/256)
__global__ __launch_bounds__(256) void k_prep(const float* __restrict__ x,
                                              unsigned short* __restrict__ xb,
                                              const float* __restrict__ W,
                                              unsigned short* __restrict__ Wt,
                                              const int* __restrict__ ei,
                                              int* __restrict__ counts) {
  const int blk = blockIdx.x;
  const int t = threadIdx.x;
  if (blk < NB_CVTX) {
    size_t i = ((size_t)blk * 256 + t) * 8;
    unsigned short o[8];
    if (i < (size_t)Mv * Cv) {
      float4 v0 = *(const float4*)(x + i);
      float4 v1 = *(const float4*)(x + i + 4);
      o[0] = f2b(v0.x); o[1] = f2b(v0.y); o[2] = f2b(v0.z); o[3] = f2b(v0.w);
      o[4] = f2b(v1.x); o[5] = f2b(v1.y); o[6] = f2b(v1.z); o[7] = f2b(v1.w);
    } else {
      for (int j = 0; j < 8; ++j) o[j] = 0;
    }
    *(uint4*)(xb + i) = *(const uint4*)o;
  } else if (blk < NB_CVTX + NB_CVTW) {
    __shared__ float s[32][33];
    const int bw = blk - NB_CVTX;
    const int n0 = (bw % 24) * 32, k0 = (bw / 24) * 32;
    const int tx = t & 31, ty = t >> 5;  // 32 x 8
#pragma unroll
    for (int i = 0; i < 4; ++i)
      s[ty + i * 8][tx] = W[(size_t)(k0 + ty + i * 8) * HD + n0 + tx];
    __syncthreads();
#pragma unroll
    for (int i = 0; i < 4; ++i)
      Wt[(size_t)(n0 + ty + i * 8) * Cv + k0 + tx] = f2b(s[tx][ty + i * 8]);
  } else {
    const int e = (blk - NB_CVTX - NB_CVTW) * 256 + t;
    if (e < ETOT) {
      int dst = (e < Ev) ? ei[Ev + e] : (e - Ev);
      atomicAdd(&counts[dst], 1);
    }
  }
}

// ------ GEMM + fused attention dots + SCATTER side-blocks ------------------
// Blocks 0..239: 256x128 GEMM tile, BK=64, 8 waves, XCD-swizzled (A reuse).
// Blocks 240..562: CSR scatter (independent work, fills idle CUs ~free).
#define NB_GEMM 240
#define NB_SCAT ((ETOT + 511) / 512)   // 323
__global__ __launch_bounds__(512) void k_gemm_sc(const unsigned short* __restrict__ A,
                                                 const unsigned short* __restrict__ Bt,
                                                 unsigned short* __restrict__ C,
                                                 const float* __restrict__ att_src,
                                                 const float* __restrict__ att_dst,
                                                 float* __restrict__ asrc,
                                                 float* __restrict__ adst,
                                                 const int* __restrict__ ei,
                                                 const int* __restrict__ offsets,
                                                 int* __restrict__ cursor,
                                                 int* __restrict__ csr) {
  if (blockIdx.x >= NB_GEMM) {
    const int e = (blockIdx.x - NB_GEMM) * 512 + threadIdx.x;
    if (e < ETOT) {
      int dst = (e < Ev) ? ei[Ev + e] : (e - Ev);
      int pos = atomicAdd(&cursor[dst], 1);
      csr[offsets[dst] + pos] = e;
    }
    return;
  }
  __shared__ unsigned short As[256 * 64];
  __shared__ unsigned short Bs[128 * 64];
  const int l0 = blockIdx.x;
  const int xcd = l0 & 7, j = l0 >> 3;        // j < 30
  const int bm = (xcd + 8 * (j / 6)) * 256;   // M-block pinned to xcd
  const int bn = (j % 6) * 128;
  const int t = threadIdx.x;
  const int w = t >> 6, l = t & 63;
  const int wr = w >> 1, wc = w & 1;          // 4 x 2 wave grid
  const int g = l >> 4, li = l & 15;
  f32x4 acc[4][4] = {};

  const int rs = t >> 3;              // staging row within 64-row issue (0..63)
  const int sl = (t & 7) ^ (rs & 7);  // pre-swizzled logical slot for source

  for (int k0 = 0; k0 < Cv; k0 += 64) {
#pragma unroll
    for (int i = 0; i < 4; ++i) {  // A: 4 issues x 64 rows
      const int r = i * 64 + rs;
      GLD16(A + (size_t)(bm + r) * Cv + k0 + sl * 8, &As[t * 8 + i * 4096]);
    }
#pragma unroll
    for (int i = 0; i < 2; ++i) {  // B: 2 issues x 64 rows
      const int r = i * 64 + rs;
      GLD16(Bt + (size_t)(bn + r) * Cv + k0 + sl * 8, &Bs[t * 8 + i * 4096]);
    }
    __syncthreads();  // drains vmcnt(0): LDS tiles ready for all waves
#pragma unroll
    for (int ks = 0; ks < 2; ++ks) {
      bf16x8 a[4], b[4];
#pragma unroll
      for (int mi = 0; mi < 4; ++mi) {
        const int row = wr * 64 + mi * 16 + li;
        const int slot = (ks * 4 + g) ^ (row & 7);
        a[mi] = *(const bf16x8*)&As[row * 64 + slot * 8];
      }
#pragma unroll
      for (int nj = 0; nj < 4; ++nj) {
        const int row = wc * 64 + nj * 16 + li;
        const int slot = (ks * 4 + g) ^ (row & 7);
        b[nj] = *(const bf16x8*)&Bs[row * 64 + slot * 8];
      }
#pragma unroll
      for (int mi = 0; mi < 4; ++mi)
#pragma unroll
        for (int nj = 0; nj < 4; ++nj)
          acc[mi][nj] = __builtin_amdgcn_mfma_f32_16x16x32_bf16(a[mi], b[nj], acc[mi][nj], 0, 0, 0);
    }
    __syncthreads();  // protect LDS before next stage
  }
  // C/D layout: col = lane&15, row = (lane>>4)*4 + reg (m89-verified)
#pragma unroll
  for (int mi = 0; mi < 4; ++mi) {
#pragma unroll
    for (int nj = 0; nj < 4; ++nj) {
      const int col = bn + wc * 64 + nj * 16 + li;
#pragma unroll
      for (int r4 = 0; r4 < 4; ++r4) {
        const int row = bm + wr * 64 + mi * 16 + g * 4 + r4;
        C[(size_t)row * HD + col] = f2b(acc[mi][nj][r4]);
      }
    }
  }
  // fused attention-dot epilogue: head covered by this wave's 64 cols
  {
    const int head = (bn >> 6) + wc;
    float aS[4], aD[4];
#pragma unroll
    for (int nj = 0; nj < 4; ++nj) {
      aS[nj] = att_src[head * Dv + nj * 16 + li];
      aD[nj] = att_dst[head * Dv + nj * 16 + li];
    }
#pragma unroll
    for (int mi = 0; mi < 4; ++mi) {
#pragma unroll
      for (int r4 = 0; r4 < 4; ++r4) {
        float vs = 0.f, vd = 0.f;
#pragma unroll
        for (int nj = 0; nj < 4; ++nj) {
          const float hv = acc[mi][nj][r4];
          vs = fmaf(hv, aS[nj], vs);
          vd = fmaf(hv, aD[nj], vd);
        }
        vs += __shfl_xor(vs, 1); vd += __shfl_xor(vd, 1);
        vs += __shfl_xor(vs, 2); vd += __shfl_xor(vd, 2);
        vs += __shfl_xor(vs, 4); vd += __shfl_xor(vd, 4);
        vs += __shfl_xor(vs, 8); vd += __shfl_xor(vd, 8);
        const int row = bm + wr * 64 + mi * 16 + g * 4 + r4;
        if (li == 0 && row < Mv) {
          asrc[(size_t)row * Hv + head] = vs;
          adst[(size_t)row * Hv + head] = vd;
        }
      }
    }
  }
}

// ---------------- CSR scan -------------------------------------------------
__global__ __launch_bounds__(1024) void k_scan(const int* __restrict__ counts,
                                               int* __restrict__ offsets) {
  __shared__ int part[1024];
  const int t = threadIdx.x;
  const int chunk = 5;  // 1024*5 >= 5000
  int begin = t * chunk;
  int end = begin + chunk;
  if (end > Nv) end = Nv;
  if (begin > Nv) begin = Nv;
  int s = 0;
  for (int i = begin; i < end; ++i) s += counts[i];
  part[t] = s;
  __syncthreads();
  for (int off = 1; off < 1024; off <<= 1) {
    int v = (t >= off) ? part[t - off] : 0;
    __syncthreads();
    part[t] += v;
    __syncthreads();
  }
  int run = (t == 0) ? 0 : part[t - 1];
  for (int i = begin; i < end; ++i) {
    offsets[i] = run;
    run += counts[i];
  }
  if (t == 0) offsets[Nv] = ETOT;
}

// ------- fused softmax + aggregation: block per (b, 4 nodes) ---------------
// 384 threads = 4 units x 96 lanes (6 waves; LDS 27.8KB -> 5 blocks/CU,
// ~30 waves/CU vs R11's 12 -> hides L2 gather latency). b = blk&1 keeps each
// XCD (blk&7) on a single batch. Phase A: per unit, 3 head-quads x 32 slots;
// one f32x4 asrc load serves 4 heads. Phase B: 96 lanes x uint4 (8 dims),
// zero-padded weights -> no guards, 2-chunk 4-deep prefetch.
#define EDGE_FMA(c, wv)                                              \
  {                                                                  \
    acc[0] = fmaf(wv, __uint_as_float((c).x << 16), acc[0]);         \
    acc[1] = fmaf(wv, __uint_as_float((c).x & 0xFFFF0000u), acc[1]); \
    acc[2] = fmaf(wv, __uint_as_float((c).y << 16), acc[2]);         \
    acc[3] = fmaf(wv, __uint_as_float((c).y & 0xFFFF0000u), acc[3]); \
    acc[4] = fmaf(wv, __uint_as_float((c).z << 16), acc[4]);         \
    acc[5] = fmaf(wv, __uint_as_float((c).z & 0xFFFF0000u), acc[5]); \
    acc[6] = fmaf(wv, __uint_as_float((c).w << 16), acc[6]);         \
    acc[7] = fmaf(wv, __uint_as_float((c).w & 0xFFFF0000u), acc[7]); \
  }

__global__ __launch_bounds__(384) void k_agg(const unsigned short* __restrict__ h2,
                                             const int* __restrict__ ei,
                                             const int* __restrict__ offsets,
                                             const int* __restrict__ csr,
                                             const float* __restrict__ asrc,
                                             const float* __restrict__ adst,
                                             const float* __restrict__ bias,
                                             float* __restrict__ out) {
  const int b = blockIdx.x & 1;            // xcd = blk&7 -> b = xcd&1: one batch per XCD
  const int n0 = (blockIdx.x >> 1) * 4;    // 4 nodes per block
  const int t = threadIdx.x;
  __shared__ int s_src[4][DEGPAD];
  __shared__ float s_w[4][Hv][DEGW];
  __shared__ float s_inv[4][16];
  __shared__ int s_off[5];
  if (t < 5) s_off[t] = offsets[n0 + t];
  __syncthreads();
  // stage all 4 CSR lists (padded with row 0)
  for (int i = t; i < 4 * DEGPAD; i += 384) {
    const int u = i / DEGPAD;
    const int ii = i - u * DEGPAD;
    const int bb = s_off[u];
    const int dd = s_off[u + 1] - bb;
    int sv = 0;
    if (ii < dd) { int e = csr[bb + ii]; sv = (e < Ev) ? ei[e] : (e - Ev); }
    s_src[u][ii] = sv;  // pad with row 0 (safe to load, weight = 0)
  }
  __syncthreads();
  // Phase A: unit u, head-quad q, slot
  {
    const int u = t / 96, rq = t % 96;
    const int q = rq >> 5, slot = rq & 31;   // q = head quad (0..2)
    const int deg = s_off[u + 1] - s_off[u];
    const int degp = (deg + 7) & ~7;
    const f32x4 adv4 = *(const f32x4*)&adst[((size_t)b * Nv + n0 + u) * Hv + q * 4];
    f32x4 ps = {0.f, 0.f, 0.f, 0.f};
    for (int i = slot; i < deg; i += 32) {
      const int src = s_src[u][i];
      const f32x4 as4 = *(const f32x4*)&asrc[((size_t)b * Nv + src) * Hv + q * 4];
#pragma unroll
      for (int jq = 0; jq < 4; ++jq) {
        float v = as4[jq] + adv4[jq];
        v = fmaxf(v, NEG * v);      // leaky_relu
        float ex = __expf(v);
        s_w[u][q * 4 + jq][i] = ex;
        ps[jq] += ex;
      }
    }
    // zero-pad weights up to degp so Phase B needs no guards
    for (int i = deg + slot; i < degp; i += 32) {
#pragma unroll
      for (int jq = 0; jq < 4; ++jq) s_w[u][q * 4 + jq][i] = 0.f;
    }
#pragma unroll
    for (int jq = 0; jq < 4; ++jq) {
      ps[jq] += __shfl_xor(ps[jq], 1);
      ps[jq] += __shfl_xor(ps[jq], 2);
      ps[jq] += __shfl_xor(ps[jq], 4);
      ps[jq] += __shfl_xor(ps[jq], 8);
      ps[jq] += __shfl_xor(ps[jq], 16);
    }
    if (slot == 0) {
      f32x4 inv;
#pragma unroll
      for (int jq = 0; jq < 4; ++jq) inv[jq] = 1.0f / (ps[jq] + 1e-16f);
      *(f32x4*)&s_inv[u][q * 4] = inv;
    }
  }
  __syncthreads();
  // Phase B: unit u, lane tl owns dims [8tl, 8tl+8); no guards (0-padded w)
  const int u = t / 96;
  const int tl = t % 96;
  const int hl = tl >> 3;  // head
  const int degp = ((s_off[u + 1] - s_off[u]) + 7) & ~7;
  float acc[8] = {};
  const unsigned short* hrow = h2 + (size_t)b * Nv * HD + tl * 8;
  uint4 cA[4], cB[4];
#pragma unroll
  for (int k = 0; k < 4; ++k)
    cA[k] = *(const uint4*)(hrow + (size_t)s_src[u][k] * HD);
  for (int base = 0; base < degp; base += 8) {
#pragma unroll
    for (int k = 0; k < 4; ++k)
      cB[k] = *(const uint4*)(hrow + (size_t)s_src[u][base + 4 + k] * HD);
    {
      const f32x4 w4 = *(const f32x4*)&s_w[u][hl][base];
      EDGE_FMA(cA[0], w4[0]); EDGE_FMA(cA[1], w4[1]);
      EDGE_FMA(cA[2], w4[2]); EDGE_FMA(cA[3], w4[3]);
    }
#pragma unroll
    for (int k = 0; k < 4; ++k)
      cA[k] = *(const uint4*)(hrow + (size_t)s_src[u][base + 8 + k] * HD);
    {
      const f32x4 w4 = *(const f32x4*)&s_w[u][hl][base + 4];
      EDGE_FMA(cB[0], w4[0]); EDGE_FMA(cB[1], w4[1]);
      EDGE_FMA(cB[2], w4[2]); EDGE_FMA(cB[3], w4[3]);
    }
  }
  const float invh = s_inv[u][hl];
  const int od = tl * 8;
  float4 o0, o1;
  o0.x = fmaf(acc[0], invh, bias[od + 0]);
  o0.y = fmaf(acc[1], invh, bias[od + 1]);
  o0.z = fmaf(acc[2], invh, bias[od + 2]);
  o0.w = fmaf(acc[3], invh, bias[od + 3]);
  o1.x = fmaf(acc[4], invh, bias[od + 4]);
  o1.y = fmaf(acc[5], invh, bias[od + 5]);
  o1.z = fmaf(acc[6], invh, bias[od + 6]);
  o1.w = fmaf(acc[7], invh, bias[od + 7]);
  float* op = out + ((size_t)b * Nv + n0 + u) * HD + od;
  *(float4*)op = o0;
  *(float4*)(op + 4) = o1;
}

extern "C" void kernel_launch(void* const* d_in, const int* in_sizes, int n_in,
                              void* d_out, int out_size, void* d_ws, size_t ws_size,
                              hipStream_t stream) {
  const float* x = (const float*)d_in[0];
  const float* W = (const float*)d_in[1];
  const float* att_src = (const float*)d_in[2];
  const float* att_dst = (const float*)d_in[3];
  const float* bias = (const float*)d_in[4];
  const int* ei = (const int*)d_in[5];
  float* out = (float*)d_out;

  // workspace layout
  unsigned short* h2 = (unsigned short*)d_ws;            // MPAD*768 bf16
  unsigned short* xbf = h2 + (size_t)MPAD * HD;          // MPAD*768 bf16
  unsigned short* wt = xbf + (size_t)MPAD * HD;          // 768*768 bf16
  float* asrc = (float*)(wt + (size_t)HD * Cv);          // 120,000 f32
  float* adst = asrc + (size_t)Bv * Nv * Hv;             // 120,000 f32
  int* counts = (int*)(adst + (size_t)Bv * Nv * Hv);     // Nv
  int* cursor = counts + Nv;                             // Nv
  int* offsets = cursor + Nv;                            // Nv+1
  int* csr = offsets + Nv + 1;                           // ETOT

  hipMemsetAsync(counts, 0, sizeof(int) * 2 * Nv, stream);

  k_prep<<<NB_CVTX + NB_CVTW + NB_CNT, 256, 0, stream>>>(x, xbf, W, wt, ei, counts);
  k_scan<<<1, 1024, 0, stream>>>(counts, offsets);
  k_gemm_sc<<<NB_GEMM + NB_SCAT, 512, 0, stream>>>(xbf, wt, h2, att_src, att_dst,
                                                   asrc, adst, ei, offsets, cursor, csr);
  k_agg<<<Bv * Nv / 4, 384, 0, stream>>>(h2, ei, offsets, csr, asrc, adst, bias, out);
}

// Round 14
// 131.935 us; speedup vs baseline: 1.0867x; 1.0228x over previous
//
#include <hip/hip_runtime.h>

#define Bv 2
#define Nv 5000
#define Cv 768
#define Hv 12
#define Dv 64
#define Ev 160000
#define ETOT (Ev + Nv)   // 165000 (edges + self loops)
#define HD 768
#define NEG 0.2f
#define Mv (Bv * Nv)     // 10000
#define MPAD 10240       // 40 * 256
#define DEGMAX 128       // max in-degree incl. self-loop; Poisson(33) tail -> safe
#define DEGPAD 144       // staging pad so depth-8 prefetch can overread (max idx 135)
#define DEGW 132         // s_w edge stride: 4*33 keeps 16B align, spreads banks

typedef __bf16 bf16x8 __attribute__((ext_vector_type(8)));
typedef float f32x4 __attribute__((ext_vector_type(4)));

// direct-to-LDS 16B async copy
#define GLD16(gsrc, ldst)                                                      \
  __builtin_amdgcn_global_load_lds(                                            \
      (const __attribute__((address_space(1))) unsigned int*)(gsrc),           \
      (__attribute__((address_space(3))) unsigned int*)(ldst), 16, 0, 0)

// f32 -> bf16 round-to-nearest-even
__device__ __forceinline__ unsigned short f2b(float f) {
  unsigned u = __float_as_uint(f);
  return (unsigned short)((u + 0x7FFFu + ((u >> 16) & 1u)) >> 16);
}

// ---- merged prep: cvt_x (3840 blocks) | cvt_wt (576) | count (645) --------
#define NB_CVTX 3840   // MPAD*HD/8/256
#define NB_CVTW 576    // (768/32)*(768/32)
#define NB_CNT  645    // ceil(ETOT/256)
__global__ __launch_bounds__(256) void k_prep(const float* __restrict__ x,
                                              unsigned short* __restrict__ xb,
                                              const float* __restrict__ W,
                                              unsigned short* __restrict__ Wt,
                                              const int* __restrict__ ei,
                                              int* __restrict__ counts) {
  const int blk = blockIdx.x;
  const int t = threadIdx.x;
  if (blk < NB_CVTX) {
    size_t i = ((size_t)blk * 256 + t) * 8;
    unsigned short o[8];
    if (i < (size_t)Mv * Cv) {
      float4 v0 = *(const float4*)(x + i);
      float4 v1 = *(const float4*)(x + i + 4);
      o[0] = f2b(v0.x); o[1] = f2b(v0.y); o[2] = f2b(v0.z); o[3] = f2b(v0.w);
      o[4] = f2b(v1.x); o[5] = f2b(v1.y); o[6] = f2b(v1.z); o[7] = f2b(v1.w);
    } else {
      for (int j = 0; j < 8; ++j) o[j] = 0;
    }
    *(uint4*)(xb + i) = *(const uint4*)o;
  } else if (blk < NB_CVTX + NB_CVTW) {
    __shared__ float s[32][33];
    const int bw = blk - NB_CVTX;
    const int n0 = (bw % 24) * 32, k0 = (bw / 24) * 32;
    const int tx = t & 31, ty = t >> 5;  // 32 x 8
#pragma unroll
    for (int i = 0; i < 4; ++i)
      s[ty + i * 8][tx] = W[(size_t)(k0 + ty + i * 8) * HD + n0 + tx];
    __syncthreads();
#pragma unroll
    for (int i = 0; i < 4; ++i)
      Wt[(size_t)(n0 + ty + i * 8) * Cv + k0 + tx] = f2b(s[tx][ty + i * 8]);
  } else {
    const int e = (blk - NB_CVTX - NB_CVTW) * 256 + t;
    if (e < ETOT) {
      int dst = (e < Ev) ? ei[Ev + e] : (e - Ev);
      atomicAdd(&counts[dst], 1);
    }
  }
}

// ------ GEMM + fused attention dots + SCATTER side-blocks ------------------
#define NB_GEMM 240
#define NB_SCAT ((ETOT + 511) / 512)   // 323
__global__ __launch_bounds__(512) void k_gemm_sc(const unsigned short* __restrict__ A,
                                                 const unsigned short* __restrict__ Bt,
                                                 unsigned short* __restrict__ C,
                                                 const float* __restrict__ att_src,
                                                 const float* __restrict__ att_dst,
                                                 float* __restrict__ asrc,
                                                 float* __restrict__ adst,
                                                 const int* __restrict__ ei,
                                                 const int* __restrict__ offsets,
                                                 int* __restrict__ cursor,
                                                 int* __restrict__ csr) {
  if (blockIdx.x >= NB_GEMM) {
    const int e = (blockIdx.x - NB_GEMM) * 512 + threadIdx.x;
    if (e < ETOT) {
      int dst = (e < Ev) ? ei[Ev + e] : (e - Ev);
      int pos = atomicAdd(&cursor[dst], 1);
      csr[offsets[dst] + pos] = e;
    }
    return;
  }
  __shared__ unsigned short As[256 * 64];
  __shared__ unsigned short Bs[128 * 64];
  const int l0 = blockIdx.x;
  const int xcd = l0 & 7, j = l0 >> 3;        // j < 30
  const int bm = (xcd + 8 * (j / 6)) * 256;   // M-block pinned to xcd
  const int bn = (j % 6) * 128;
  const int t = threadIdx.x;
  const int w = t >> 6, l = t & 63;
  const int wr = w >> 1, wc = w & 1;          // 4 x 2 wave grid
  const int g = l >> 4, li = l & 15;
  f32x4 acc[4][4] = {};

  const int rs = t >> 3;              // staging row within 64-row issue (0..63)
  const int sl = (t & 7) ^ (rs & 7);  // pre-swizzled logical slot for source

  for (int k0 = 0; k0 < Cv; k0 += 64) {
#pragma unroll
    for (int i = 0; i < 4; ++i) {  // A: 4 issues x 64 rows
      const int r = i * 64 + rs;
      GLD16(A + (size_t)(bm + r) * Cv + k0 + sl * 8, &As[t * 8 + i * 4096]);
    }
#pragma unroll
    for (int i = 0; i < 2; ++i) {  // B: 2 issues x 64 rows
      const int r = i * 64 + rs;
      GLD16(Bt + (size_t)(bn + r) * Cv + k0 + sl * 8, &Bs[t * 8 + i * 4096]);
    }
    __syncthreads();  // drains vmcnt(0): LDS tiles ready for all waves
#pragma unroll
    for (int ks = 0; ks < 2; ++ks) {
      bf16x8 a[4], b[4];
#pragma unroll
      for (int mi = 0; mi < 4; ++mi) {
        const int row = wr * 64 + mi * 16 + li;
        const int slot = (ks * 4 + g) ^ (row & 7);
        a[mi] = *(const bf16x8*)&As[row * 64 + slot * 8];
      }
#pragma unroll
      for (int nj = 0; nj < 4; ++nj) {
        const int row = wc * 64 + nj * 16 + li;
        const int slot = (ks * 4 + g) ^ (row & 7);
        b[nj] = *(const bf16x8*)&Bs[row * 64 + slot * 8];
      }
#pragma unroll
      for (int mi = 0; mi < 4; ++mi)
#pragma unroll
        for (int nj = 0; nj < 4; ++nj)
          acc[mi][nj] = __builtin_amdgcn_mfma_f32_16x16x32_bf16(a[mi], b[nj], acc[mi][nj], 0, 0, 0);
    }
    __syncthreads();  // protect LDS before next stage
  }
  // C/D layout: col = lane&15, row = (lane>>4)*4 + reg (m89-verified)
#pragma unroll
  for (int mi = 0; mi < 4; ++mi) {
#pragma unroll
    for (int nj = 0; nj < 4; ++nj) {
      const int col = bn + wc * 64 + nj * 16 + li;
#pragma unroll
      for (int r4 = 0; r4 < 4; ++r4) {
        const int row = bm + wr * 64 + mi * 16 + g * 4 + r4;
        C[(size_t)row * HD + col] = f2b(acc[mi][nj][r4]);
      }
    }
  }
  // fused attention-dot epilogue: head covered by this wave's 64 cols
  {
    const int head = (bn >> 6) + wc;
    float aS[4], aD[4];
#pragma unroll
    for (int nj = 0; nj < 4; ++nj) {
      aS[nj] = att_src[head * Dv + nj * 16 + li];
      aD[nj] = att_dst[head * Dv + nj * 16 + li];
    }
#pragma unroll
    for (int mi = 0; mi < 4; ++mi) {
#pragma unroll
      for (int r4 = 0; r4 < 4; ++r4) {
        float vs = 0.f, vd = 0.f;
#pragma unroll
        for (int nj = 0; nj < 4; ++nj) {
          const float hv = acc[mi][nj][r4];
          vs = fmaf(hv, aS[nj], vs);
          vd = fmaf(hv, aD[nj], vd);
        }
        vs += __shfl_xor(vs, 1); vd += __shfl_xor(vd, 1);
        vs += __shfl_xor(vs, 2); vd += __shfl_xor(vd, 2);
        vs += __shfl_xor(vs, 4); vd += __shfl_xor(vd, 4);
        vs += __shfl_xor(vs, 8); vd += __shfl_xor(vd, 8);
        const int row = bm + wr * 64 + mi * 16 + g * 4 + r4;
        if (li == 0 && row < Mv) {
          asrc[(size_t)row * Hv + head] = vs;
          adst[(size_t)row * Hv + head] = vd;
        }
      }
    }
  }
}

// ---------------- CSR scan (also zeroes cursor) ----------------------------
__global__ __launch_bounds__(1024) void k_scan(const int* __restrict__ counts,
                                               int* __restrict__ offsets,
                                               int* __restrict__ cursor) {
  __shared__ int part[1024];
  const int t = threadIdx.x;
  const int chunk = 5;  // 1024*5 >= 5000
  int begin = t * chunk;
  int end = begin + chunk;
  if (end > Nv) end = Nv;
  if (begin > Nv) begin = Nv;
  int s = 0;
  for (int i = begin; i < end; ++i) { s += counts[i]; cursor[i] = 0; }
  part[t] = s;
  __syncthreads();
  for (int off = 1; off < 1024; off <<= 1) {
    int v = (t >= off) ? part[t - off] : 0;
    __syncthreads();
    part[t] += v;
    __syncthreads();
  }
  int run = (t == 0) ? 0 : part[t - 1];
  for (int i = begin; i < end; ++i) {
    offsets[i] = run;
    run += counts[i];
  }
  if (t == 0) offsets[Nv] = ETOT;
}

// ------- fused softmax + aggregation: block per (b, n-pair), depth-8 -------
// 192 threads = 2 nodes x 96 lanes, 2500 blocks. Phase B: two 8-deep uint4
// buffers; 8 loads of chunk i+1 in flight while FMA-ing chunk i.
// PADDING CONTRACT: loop strides 16 -> degp rounded to 16 and s_w zeroed on
// [deg, degp) in BOTH phases (R13 bug: rounded to 8, read garbage LDS).
#define EDGE_FMA(c, wv)                                              \
  {                                                                  \
    acc[0] = fmaf(wv, __uint_as_float((c).x << 16), acc[0]);         \
    acc[1] = fmaf(wv, __uint_as_float((c).x & 0xFFFF0000u), acc[1]); \
    acc[2] = fmaf(wv, __uint_as_float((c).y << 16), acc[2]);         \
    acc[3] = fmaf(wv, __uint_as_float((c).y & 0xFFFF0000u), acc[3]); \
    acc[4] = fmaf(wv, __uint_as_float((c).z << 16), acc[4]);         \
    acc[5] = fmaf(wv, __uint_as_float((c).z & 0xFFFF0000u), acc[5]); \
    acc[6] = fmaf(wv, __uint_as_float((c).w << 16), acc[6]);         \
    acc[7] = fmaf(wv, __uint_as_float((c).w & 0xFFFF0000u), acc[7]); \
  }

__global__ __launch_bounds__(192) void k_agg(const unsigned short* __restrict__ h2,
                                             const int* __restrict__ ei,
                                             const int* __restrict__ offsets,
                                             const int* __restrict__ csr,
                                             const float* __restrict__ asrc,
                                             const float* __restrict__ adst,
                                             const float* __restrict__ bias,
                                             float* __restrict__ out) {
  const int xcd = blockIdx.x & 7;
  const int idx = blockIdx.x >> 3;        // 0..624
  const int b = xcd >> 2;
  const int pair = (xcd & 3) * 625 + idx; // 0..2499
  const int n0 = pair * 2;                // block handles n0, n0+1
  const int t = threadIdx.x;
  __shared__ int s_src[2][DEGPAD];
  __shared__ float s_w[2][Hv][DEGW];
  __shared__ float s_inv[2][16];
  const int beg0 = offsets[n0], beg1 = offsets[n0 + 1], end1 = offsets[n0 + 2];
  const int d0 = beg1 - beg0, d1 = end1 - beg1;  // <= DEGMAX
  for (int i = t; i < 2 * DEGPAD; i += 192) {
    const int jn = i >= DEGPAD;
    const int ii = i - jn * DEGPAD;
    const int dd = jn ? d1 : d0;
    const int bb = jn ? beg1 : beg0;
    int sv = 0;
    if (ii < dd) { int e = csr[bb + ii]; sv = (e < Ev) ? ei[e] : (e - Ev); }
    s_src[jn][ii] = sv;  // pad with row 0 (safe to load, weight = 0)
  }
  __syncthreads();
  // Phase A: (node jn, head-quad q, slot): one f32x4 asrc load serves 4 heads
  {
    const int jn = t / 96, rq = t % 96;
    const int q = rq >> 5, slot = rq & 31;   // q = head quad (0..2)
    const int deg = jn ? d1 : d0;
    const int degp = (deg + 15) & ~15;       // 16-aligned: matches Phase B stride
    const f32x4 adv4 = *(const f32x4*)&adst[((size_t)b * Nv + n0 + jn) * Hv + q * 4];
    f32x4 ps = {0.f, 0.f, 0.f, 0.f};
    for (int i = slot; i < deg; i += 32) {
      const int src = s_src[jn][i];
      const f32x4 as4 = *(const f32x4*)&asrc[((size_t)b * Nv + src) * Hv + q * 4];
#pragma unroll
      for (int jq = 0; jq < 4; ++jq) {
        float v = as4[jq] + adv4[jq];
        v = fmaxf(v, NEG * v);      // leaky_relu
        float ex = __expf(v);
        s_w[jn][q * 4 + jq][i] = ex;
        ps[jq] += ex;
      }
    }
    for (int i = deg + slot; i < degp; i += 32) {
#pragma unroll
      for (int jq = 0; jq < 4; ++jq) s_w[jn][q * 4 + jq][i] = 0.f;
    }
#pragma unroll
    for (int jq = 0; jq < 4; ++jq) {
      ps[jq] += __shfl_xor(ps[jq], 1);
      ps[jq] += __shfl_xor(ps[jq], 2);
      ps[jq] += __shfl_xor(ps[jq], 4);
      ps[jq] += __shfl_xor(ps[jq], 8);
      ps[jq] += __shfl_xor(ps[jq], 16);
    }
    if (slot == 0) {
      f32x4 inv;
#pragma unroll
      for (int jq = 0; jq < 4; ++jq) inv[jq] = 1.0f / (ps[jq] + 1e-16f);
      *(f32x4*)&s_inv[jn][q * 4] = inv;
    }
  }
  __syncthreads();
  // Phase B: node jn, lane tl owns dims [8tl, 8tl+8); no guards (0-padded w)
  const int jn = t >= 96;
  const int tl = t - jn * 96;
  const int hl = tl >> 3;  // head
  const int degp = ((jn ? d1 : d0) + 15) & ~15;   // 16-aligned (R13 fix)
  float acc[8] = {};
  const unsigned short* hrow = h2 + (size_t)b * Nv * HD + tl * 8;
  uint4 cA[8], cB[8];
#pragma unroll
  for (int k = 0; k < 8; ++k)
    cA[k] = *(const uint4*)(hrow + (size_t)s_src[jn][k] * HD);
  for (int base = 0; base < degp; base += 16) {
    // issue chunk i+1 (8 loads) before consuming chunk i
#pragma unroll
    for (int k = 0; k < 8; ++k)
      cB[k] = *(const uint4*)(hrow + (size_t)s_src[jn][base + 8 + k] * HD);
    {
      const f32x4 wa = *(const f32x4*)&s_w[jn][hl][base];
      const f32x4 wb = *(const f32x4*)&s_w[jn][hl][base + 4];
      EDGE_FMA(cA[0], wa[0]); EDGE_FMA(cA[1], wa[1]);
      EDGE_FMA(cA[2], wa[2]); EDGE_FMA(cA[3], wa[3]);
      EDGE_FMA(cA[4], wb[0]); EDGE_FMA(cA[5], wb[1]);
      EDGE_FMA(cA[6], wb[2]); EDGE_FMA(cA[7], wb[3]);
    }
#pragma unroll
    for (int k = 0; k < 8; ++k)
      cA[k] = *(const uint4*)(hrow + (size_t)s_src[jn][base + 16 + k] * HD);  // max 135 < DEGPAD
    {
      const f32x4 wa = *(const f32x4*)&s_w[jn][hl][base + 8];
      const f32x4 wb = *(const f32x4*)&s_w[jn][hl][base + 12];
      EDGE_FMA(cB[0], wa[0]); EDGE_FMA(cB[1], wa[1]);
      EDGE_FMA(cB[2], wa[2]); EDGE_FMA(cB[3], wa[3]);
      EDGE_FMA(cB[4], wb[0]); EDGE_FMA(cB[5], wb[1]);
      EDGE_FMA(cB[6], wb[2]); EDGE_FMA(cB[7], wb[3]);
    }
  }
  const float invh = s_inv[jn][hl];
  const int od = tl * 8;
  float4 o0, o1;
  o0.x = fmaf(acc[0], invh, bias[od + 0]);
  o0.y = fmaf(acc[1], invh, bias[od + 1]);
  o0.z = fmaf(acc[2], invh, bias[od + 2]);
  o0.w = fmaf(acc[3], invh, bias[od + 3]);
  o1.x = fmaf(acc[4], invh, bias[od + 4]);
  o1.y = fmaf(acc[5], invh, bias[od + 5]);
  o1.z = fmaf(acc[6], invh, bias[od + 6]);
  o1.w = fmaf(acc[7], invh, bias[od + 7]);
  float* op = out + ((size_t)b * Nv + n0 + jn) * HD + od;
  *(float4*)op = o0;
  *(float4*)(op + 4) = o1;
}

extern "C" void kernel_launch(void* const* d_in, const int* in_sizes, int n_in,
                              void* d_out, int out_size, void* d_ws, size_t ws_size,
                              hipStream_t stream) {
  const float* x = (const float*)d_in[0];
  const float* W = (const float*)d_in[1];
  const float* att_src = (const float*)d_in[2];
  const float* att_dst = (const float*)d_in[3];
  const float* bias = (const float*)d_in[4];
  const int* ei = (const int*)d_in[5];
  float* out = (float*)d_out;

  // workspace layout
  unsigned short* h2 = (unsigned short*)d_ws;            // MPAD*768 bf16
  unsigned short* xbf = h2 + (size_t)MPAD * HD;          // MPAD*768 bf16
  unsigned short* wt = xbf + (size_t)MPAD * HD;          // 768*768 bf16
  float* asrc = (float*)(wt + (size_t)HD * Cv);          // 120,000 f32
  float* adst = asrc + (size_t)Bv * Nv * Hv;             // 120,000 f32
  int* counts = (int*)(adst + (size_t)Bv * Nv * Hv);     // Nv
  int* cursor = counts + Nv;                             // Nv
  int* offsets = cursor + Nv;                            // Nv+1
  int* csr = offsets + Nv + 1;                           // ETOT

  hipMemsetAsync(counts, 0, sizeof(int) * Nv, stream);

  k_prep<<<NB_CVTX + NB_CVTW + NB_CNT, 256, 0, stream>>>(x, xbf, W, wt, ei, counts);
  k_scan<<<1, 1024, 0, stream>>>(counts, offsets, cursor);
  k_gemm_sc<<<NB_GEMM + NB_SCAT, 512, 0, stream>>>(xbf, wt, h2, att_src, att_dst,
                                                   asrc, adst, ei, offsets, cursor, csr);
  k_agg<<<Bv * Nv / 2, 192, 0, stream>>>(h2, ei, offsets, csr, asrc, adst, bias, out);
}

// Round 15
// 98.843 us; speedup vs baseline: 1.4505x; 1.3348x over previous
//
#include <hip/hip_runtime.h>

#define Bv 2
#define Nv 5000
#define Cv 768
#define Hv 12
#define Dv 64
#define Ev 160000
#define ETOT (Ev + Nv)   // 165000 (edges + self loops)
#define HD 768
#define NEG 0.2f
#define Mv (Bv * Nv)     // 10000
#define MPAD 10240       // 40 * 256
#define DEGMAX 128       // max in-degree incl. self-loop; Poisson(33) tail -> safe
#define DEGPAD 136       // staging pad so 4-deep prefetch can overread (max idx 131)
#define DEGW 132         // s_w edge stride: 4*33 keeps 16B align, spreads banks

typedef __bf16 bf16x8 __attribute__((ext_vector_type(8)));
typedef float f32x4 __attribute__((ext_vector_type(4)));

// direct-to-LDS 16B async copy
#define GLD16(gsrc, ldst)                                                      \
  __builtin_amdgcn_global_load_lds(                                            \
      (const __attribute__((address_space(1))) unsigned int*)(gsrc),           \
      (__attribute__((address_space(3))) unsigned int*)(ldst), 16, 0, 0)

// f32 -> bf16 round-to-nearest-even
__device__ __forceinline__ unsigned short f2b(float f) {
  unsigned u = __float_as_uint(f);
  return (unsigned short)((u + 0x7FFFu + ((u >> 16) & 1u)) >> 16);
}

// ---- merged prep: cvt_x | cvt_wt | count+scatter (padded dense CSR) -------
// csrp[dst][DEGMAX]: pos = atomicAdd(cnt[dst]) -> one pass builds counts AND
// edge lists; no prefix-sum, no separate scatter kernel.
#define NB_CVTX 3840   // MPAD*HD/8/256
#define NB_CVTW 576    // (768/32)*(768/32)
#define NB_CNT  645    // ceil(ETOT/256)
__global__ __launch_bounds__(256) void k_prep(const float* __restrict__ x,
                                              unsigned short* __restrict__ xb,
                                              const float* __restrict__ W,
                                              unsigned short* __restrict__ Wt,
                                              const int* __restrict__ ei,
                                              int* __restrict__ cnt,
                                              int* __restrict__ csrp) {
  const int blk = blockIdx.x;
  const int t = threadIdx.x;
  if (blk < NB_CVTX) {
    size_t i = ((size_t)blk * 256 + t) * 8;
    unsigned short o[8];
    if (i < (size_t)Mv * Cv) {
      float4 v0 = *(const float4*)(x + i);
      float4 v1 = *(const float4*)(x + i + 4);
      o[0] = f2b(v0.x); o[1] = f2b(v0.y); o[2] = f2b(v0.z); o[3] = f2b(v0.w);
      o[4] = f2b(v1.x); o[5] = f2b(v1.y); o[6] = f2b(v1.z); o[7] = f2b(v1.w);
    } else {
      for (int j = 0; j < 8; ++j) o[j] = 0;
    }
    *(uint4*)(xb + i) = *(const uint4*)o;
  } else if (blk < NB_CVTX + NB_CVTW) {
    __shared__ float s[32][33];
    const int bw = blk - NB_CVTX;
    const int n0 = (bw % 24) * 32, k0 = (bw / 24) * 32;
    const int tx = t & 31, ty = t >> 5;  // 32 x 8
#pragma unroll
    for (int i = 0; i < 4; ++i)
      s[ty + i * 8][tx] = W[(size_t)(k0 + ty + i * 8) * HD + n0 + tx];
    __syncthreads();
#pragma unroll
    for (int i = 0; i < 4; ++i)
      Wt[(size_t)(n0 + ty + i * 8) * Cv + k0 + tx] = f2b(s[tx][ty + i * 8]);
  } else {
    const int e = (blk - NB_CVTX - NB_CVTW) * 256 + t;
    if (e < ETOT) {
      int dst = (e < Ev) ? ei[Ev + e] : (e - Ev);
      int src = (e < Ev) ? ei[e] : (e - Ev);
      int pos = atomicAdd(&cnt[dst], 1);
      csrp[dst * DEGMAX + pos] = src;  // store src directly (skip e->src later)
    }
  }
}

// ------ GEMM + fused attention dots: h2 = xb @ Wt^T; asrc/adst epilogue ----
// 256x128 tile, BK=64, 8 waves (4x2), 512 threads, 1D grid 240.
// XCD swizzle: all 6 N-tiles of one M-block land on the same XCD.
__global__ __launch_bounds__(512) void k_gemm_mfma(const unsigned short* __restrict__ A,
                                                   const unsigned short* __restrict__ Bt,
                                                   unsigned short* __restrict__ C,
                                                   const float* __restrict__ att_src,
                                                   const float* __restrict__ att_dst,
                                                   float* __restrict__ asrc,
                                                   float* __restrict__ adst) {
  __shared__ unsigned short As[256 * 64];
  __shared__ unsigned short Bs[128 * 64];
  const int l0 = blockIdx.x;
  const int xcd = l0 & 7, j = l0 >> 3;        // j < 30
  const int bm = (xcd + 8 * (j / 6)) * 256;   // M-block pinned to xcd
  const int bn = (j % 6) * 128;
  const int t = threadIdx.x;
  const int w = t >> 6, l = t & 63;
  const int wr = w >> 1, wc = w & 1;          // 4 x 2 wave grid
  const int g = l >> 4, li = l & 15;
  f32x4 acc[4][4] = {};

  const int rs = t >> 3;              // staging row within 64-row issue (0..63)
  const int sl = (t & 7) ^ (rs & 7);  // pre-swizzled logical slot for source

  for (int k0 = 0; k0 < Cv; k0 += 64) {
#pragma unroll
    for (int i = 0; i < 4; ++i) {  // A: 4 issues x 64 rows
      const int r = i * 64 + rs;
      GLD16(A + (size_t)(bm + r) * Cv + k0 + sl * 8, &As[t * 8 + i * 4096]);
    }
#pragma unroll
    for (int i = 0; i < 2; ++i) {  // B: 2 issues x 64 rows
      const int r = i * 64 + rs;
      GLD16(Bt + (size_t)(bn + r) * Cv + k0 + sl * 8, &Bs[t * 8 + i * 4096]);
    }
    __syncthreads();  // drains vmcnt(0): LDS tiles ready for all waves
#pragma unroll
    for (int ks = 0; ks < 2; ++ks) {
      bf16x8 a[4], b[4];
#pragma unroll
      for (int mi = 0; mi < 4; ++mi) {
        const int row = wr * 64 + mi * 16 + li;
        const int slot = (ks * 4 + g) ^ (row & 7);
        a[mi] = *(const bf16x8*)&As[row * 64 + slot * 8];
      }
#pragma unroll
      for (int nj = 0; nj < 4; ++nj) {
        const int row = wc * 64 + nj * 16 + li;
        const int slot = (ks * 4 + g) ^ (row & 7);
        b[nj] = *(const bf16x8*)&Bs[row * 64 + slot * 8];
      }
#pragma unroll
      for (int mi = 0; mi < 4; ++mi)
#pragma unroll
        for (int nj = 0; nj < 4; ++nj)
          acc[mi][nj] = __builtin_amdgcn_mfma_f32_16x16x32_bf16(a[mi], b[nj], acc[mi][nj], 0, 0, 0);
    }
    __syncthreads();  // protect LDS before next stage
  }
  // C/D layout: col = lane&15, row = (lane>>4)*4 + reg (m89-verified)
#pragma unroll
  for (int mi = 0; mi < 4; ++mi) {
#pragma unroll
    for (int nj = 0; nj < 4; ++nj) {
      const int col = bn + wc * 64 + nj * 16 + li;
#pragma unroll
      for (int r4 = 0; r4 < 4; ++r4) {
        const int row = bm + wr * 64 + mi * 16 + g * 4 + r4;
        C[(size_t)row * HD + col] = f2b(acc[mi][nj][r4]);
      }
    }
  }
  // fused attention-dot epilogue: head covered by this wave's 64 cols
  {
    const int head = (bn >> 6) + wc;
    float aS[4], aD[4];
#pragma unroll
    for (int nj = 0; nj < 4; ++nj) {
      aS[nj] = att_src[head * Dv + nj * 16 + li];
      aD[nj] = att_dst[head * Dv + nj * 16 + li];
    }
#pragma unroll
    for (int mi = 0; mi < 4; ++mi) {
#pragma unroll
      for (int r4 = 0; r4 < 4; ++r4) {
        float vs = 0.f, vd = 0.f;
#pragma unroll
        for (int nj = 0; nj < 4; ++nj) {
          const float hv = acc[mi][nj][r4];
          vs = fmaf(hv, aS[nj], vs);
          vd = fmaf(hv, aD[nj], vd);
        }
        vs += __shfl_xor(vs, 1); vd += __shfl_xor(vd, 1);
        vs += __shfl_xor(vs, 2); vd += __shfl_xor(vd, 2);
        vs += __shfl_xor(vs, 4); vd += __shfl_xor(vd, 4);
        vs += __shfl_xor(vs, 8); vd += __shfl_xor(vd, 8);
        const int row = bm + wr * 64 + mi * 16 + g * 4 + r4;
        if (li == 0 && row < Mv) {
          asrc[(size_t)row * Hv + head] = vs;
          adst[(size_t)row * Hv + head] = vd;
        }
      }
    }
  }
}

// ------- fused softmax + aggregation: block per (b, n-pair) ----------------
// R11 geometry (best measured: 54.5us, 48 VGPR). 192 threads = 2 nodes x 96
// lanes, 2500 blocks, XCD pinned on batch. Phase A: (node, head-quad, slot),
// one f32x4 asrc load serves 4 heads. Phase B: lane owns 8 dims (uint4/edge),
// zero-padded weights (8-aligned degp matches stride-8 loop), 2-chunk
// 4-deep prefetch. Edges come from padded dense CSR csrp[n][128].
#define EDGE_FMA(c, wv)                                              \
  {                                                                  \
    acc[0] = fmaf(wv, __uint_as_float((c).x << 16), acc[0]);         \
    acc[1] = fmaf(wv, __uint_as_float((c).x & 0xFFFF0000u), acc[1]); \
    acc[2] = fmaf(wv, __uint_as_float((c).y << 16), acc[2]);         \
    acc[3] = fmaf(wv, __uint_as_float((c).y & 0xFFFF0000u), acc[3]); \
    acc[4] = fmaf(wv, __uint_as_float((c).z << 16), acc[4]);         \
    acc[5] = fmaf(wv, __uint_as_float((c).z & 0xFFFF0000u), acc[5]); \
    acc[6] = fmaf(wv, __uint_as_float((c).w << 16), acc[6]);         \
    acc[7] = fmaf(wv, __uint_as_float((c).w & 0xFFFF0000u), acc[7]); \
  }

__global__ __launch_bounds__(192) void k_agg(const unsigned short* __restrict__ h2,
                                             const int* __restrict__ cnt,
                                             const int* __restrict__ csrp,
                                             const float* __restrict__ asrc,
                                             const float* __restrict__ adst,
                                             const float* __restrict__ bias,
                                             float* __restrict__ out) {
  const int xcd = blockIdx.x & 7;
  const int idx = blockIdx.x >> 3;        // 0..624
  const int b = xcd >> 2;
  const int pair = (xcd & 3) * 625 + idx; // 0..2499
  const int n0 = pair * 2;                // block handles n0, n0+1
  const int t = threadIdx.x;
  __shared__ int s_src[2][DEGPAD];
  __shared__ float s_w[2][Hv][DEGW];
  __shared__ float s_inv[2][16];
  const int d0 = cnt[n0], d1 = cnt[n0 + 1];  // <= DEGMAX
  for (int i = t; i < 2 * DEGPAD; i += 192) {
    const int jn = i >= DEGPAD;
    const int ii = i - jn * DEGPAD;
    const int dd = jn ? d1 : d0;
    int sv = 0;
    if (ii < dd) sv = csrp[(n0 + jn) * DEGMAX + ii];
    s_src[jn][ii] = sv;  // pad with row 0 (safe to load, weight = 0)
  }
  __syncthreads();
  // Phase A: (node jn, head-quad q, slot): one f32x4 asrc load serves 4 heads
  {
    const int jn = t / 96, rq = t % 96;
    const int q = rq >> 5, slot = rq & 31;   // q = head quad (0..2)
    const int deg = jn ? d1 : d0;
    const int degp = (deg + 7) & ~7;
    const f32x4 adv4 = *(const f32x4*)&adst[((size_t)b * Nv + n0 + jn) * Hv + q * 4];
    f32x4 ps = {0.f, 0.f, 0.f, 0.f};
    for (int i = slot; i < deg; i += 32) {
      const int src = s_src[jn][i];
      const f32x4 as4 = *(const f32x4*)&asrc[((size_t)b * Nv + src) * Hv + q * 4];
#pragma unroll
      for (int jq = 0; jq < 4; ++jq) {
        float v = as4[jq] + adv4[jq];
        v = fmaxf(v, NEG * v);      // leaky_relu
        float ex = __expf(v);
        s_w[jn][q * 4 + jq][i] = ex;
        ps[jq] += ex;
      }
    }
    for (int i = deg + slot; i < degp; i += 32) {
#pragma unroll
      for (int jq = 0; jq < 4; ++jq) s_w[jn][q * 4 + jq][i] = 0.f;
    }
#pragma unroll
    for (int jq = 0; jq < 4; ++jq) {
      ps[jq] += __shfl_xor(ps[jq], 1);
      ps[jq] += __shfl_xor(ps[jq], 2);
      ps[jq] += __shfl_xor(ps[jq], 4);
      ps[jq] += __shfl_xor(ps[jq], 8);
      ps[jq] += __shfl_xor(ps[jq], 16);
    }
    if (slot == 0) {
      f32x4 inv;
#pragma unroll
      for (int jq = 0; jq < 4; ++jq) inv[jq] = 1.0f / (ps[jq] + 1e-16f);
      *(f32x4*)&s_inv[jn][q * 4] = inv;
    }
  }
  __syncthreads();
  // Phase B: node jn, lane tl owns dims [8tl, 8tl+8); no guards (0-padded w)
  const int jn = t >= 96;
  const int tl = t - jn * 96;
  const int hl = tl >> 3;  // head
  const int degp = ((jn ? d1 : d0) + 7) & ~7;
  float acc[8] = {};
  const unsigned short* hrow = h2 + (size_t)b * Nv * HD + tl * 8;
  uint4 cA[4], cB[4];
#pragma unroll
  for (int k = 0; k < 4; ++k)
    cA[k] = *(const uint4*)(hrow + (size_t)s_src[jn][k] * HD);
  for (int base = 0; base < degp; base += 8) {
#pragma unroll
    for (int k = 0; k < 4; ++k)
      cB[k] = *(const uint4*)(hrow + (size_t)s_src[jn][base + 4 + k] * HD);
    {
      const f32x4 w4 = *(const f32x4*)&s_w[jn][hl][base];
      EDGE_FMA(cA[0], w4[0]); EDGE_FMA(cA[1], w4[1]);
      EDGE_FMA(cA[2], w4[2]); EDGE_FMA(cA[3], w4[3]);
    }
#pragma unroll
    for (int k = 0; k < 4; ++k)
      cA[k] = *(const uint4*)(hrow + (size_t)s_src[jn][base + 8 + k] * HD);  // max 131 < DEGPAD
    {
      const f32x4 w4 = *(const f32x4*)&s_w[jn][hl][base + 4];
      EDGE_FMA(cB[0], w4[0]); EDGE_FMA(cB[1], w4[1]);
      EDGE_FMA(cB[2], w4[2]); EDGE_FMA(cB[3], w4[3]);
    }
  }
  const float invh = s_inv[jn][hl];
  const int od = tl * 8;
  float4 o0, o1;
  o0.x = fmaf(acc[0], invh, bias[od + 0]);
  o0.y = fmaf(acc[1], invh, bias[od + 1]);
  o0.z = fmaf(acc[2], invh, bias[od + 2]);
  o0.w = fmaf(acc[3], invh, bias[od + 3]);
  o1.x = fmaf(acc[4], invh, bias[od + 4]);
  o1.y = fmaf(acc[5], invh, bias[od + 5]);
  o1.z = fmaf(acc[6], invh, bias[od + 6]);
  o1.w = fmaf(acc[7], invh, bias[od + 7]);
  float* op = out + ((size_t)b * Nv + n0 + jn) * HD + od;
  *(float4*)op = o0;
  *(float4*)(op + 4) = o1;
}

extern "C" void kernel_launch(void* const* d_in, const int* in_sizes, int n_in,
                              void* d_out, int out_size, void* d_ws, size_t ws_size,
                              hipStream_t stream) {
  const float* x = (const float*)d_in[0];
  const float* W = (const float*)d_in[1];
  const float* att_src = (const float*)d_in[2];
  const float* att_dst = (const float*)d_in[3];
  const float* bias = (const float*)d_in[4];
  const int* ei = (const int*)d_in[5];
  float* out = (float*)d_out;

  // workspace layout
  unsigned short* h2 = (unsigned short*)d_ws;            // MPAD*768 bf16
  unsigned short* xbf = h2 + (size_t)MPAD * HD;          // MPAD*768 bf16
  unsigned short* wt = xbf + (size_t)MPAD * HD;          // 768*768 bf16
  float* asrc = (float*)(wt + (size_t)HD * Cv);          // 120,000 f32
  float* adst = asrc + (size_t)Bv * Nv * Hv;             // 120,000 f32
  int* cnt = (int*)(adst + (size_t)Bv * Nv * Hv);        // Nv (count AND cursor)
  int* csrp = cnt + Nv;                                  // Nv*DEGMAX padded CSR

  hipMemsetAsync(cnt, 0, sizeof(int) * Nv, stream);

  k_prep<<<NB_CVTX + NB_CVTW + NB_CNT, 256, 0, stream>>>(x, xbf, W, wt, ei, cnt, csrp);
  k_gemm_mfma<<<240, 512, 0, stream>>>(xbf, wt, h2, att_src, att_dst, asrc, adst);
  k_agg<<<Bv * Nv / 2, 192, 0, stream>>>(h2, cnt, csrp, asrc, adst, bias, out);
}

// Round 16
// 97.537 us; speedup vs baseline: 1.4699x; 1.0134x over previous
//
#include <hip/hip_runtime.h>

#define Bv 2
#define Nv 5000
#define Cv 768
#define Hv 12
#define Dv 64
#define Ev 160000
#define ETOT (Ev + Nv)   // 165000 (edges + self loops)
#define HD 768
#define NEG 0.2f
#define Mv (Bv * Nv)     // 10000
#define MPAD 10240       // 40 * 256
#define DEGMAX 128       // max in-degree incl. self-loop; Poisson(33) tail -> safe
#define DEGPAD 136       // staging pad so 4-deep prefetch can overread (max idx 131)
#define DEGW 132         // s_w edge stride: 4*33 keeps 16B align, spreads banks

typedef __bf16 bf16x8 __attribute__((ext_vector_type(8)));
typedef float f32x4 __attribute__((ext_vector_type(4)));

// direct-to-LDS 16B async copy
#define GLD16(gsrc, ldst)                                                      \
  __builtin_amdgcn_global_load_lds(                                            \
      (const __attribute__((address_space(1))) unsigned int*)(gsrc),           \
      (__attribute__((address_space(3))) unsigned int*)(ldst), 16, 0, 0)

// f32 -> bf16 round-to-nearest-even
__device__ __forceinline__ unsigned short f2b(float f) {
  unsigned u = __float_as_uint(f);
  return (unsigned short)((u + 0x7FFFu + ((u >> 16) & 1u)) >> 16);
}

// ---- merged prep: cvt_x | cvt_wt | count+scatter (padded dense CSR) -------
#define NB_CVTX 3840   // MPAD*HD/8/256
#define NB_CVTW 576    // (768/32)*(768/32)
#define NB_CNT  645    // ceil(ETOT/256)
__global__ __launch_bounds__(256) void k_prep(const float* __restrict__ x,
                                              unsigned short* __restrict__ xb,
                                              const float* __restrict__ W,
                                              unsigned short* __restrict__ Wt,
                                              const int* __restrict__ ei,
                                              int* __restrict__ cnt,
                                              int* __restrict__ csrp) {
  const int blk = blockIdx.x;
  const int t = threadIdx.x;
  if (blk < NB_CVTX) {
    size_t i = ((size_t)blk * 256 + t) * 8;
    unsigned short o[8];
    if (i < (size_t)Mv * Cv) {
      float4 v0 = *(const float4*)(x + i);
      float4 v1 = *(const float4*)(x + i + 4);
      o[0] = f2b(v0.x); o[1] = f2b(v0.y); o[2] = f2b(v0.z); o[3] = f2b(v0.w);
      o[4] = f2b(v1.x); o[5] = f2b(v1.y); o[6] = f2b(v1.z); o[7] = f2b(v1.w);
    } else {
      for (int j = 0; j < 8; ++j) o[j] = 0;
    }
    *(uint4*)(xb + i) = *(const uint4*)o;
  } else if (blk < NB_CVTX + NB_CVTW) {
    __shared__ float s[32][33];
    const int bw = blk - NB_CVTX;
    const int n0 = (bw % 24) * 32, k0 = (bw / 24) * 32;
    const int tx = t & 31, ty = t >> 5;  // 32 x 8
#pragma unroll
    for (int i = 0; i < 4; ++i)
      s[ty + i * 8][tx] = W[(size_t)(k0 + ty + i * 8) * HD + n0 + tx];
    __syncthreads();
#pragma unroll
    for (int i = 0; i < 4; ++i)
      Wt[(size_t)(n0 + ty + i * 8) * Cv + k0 + tx] = f2b(s[tx][ty + i * 8]);
  } else {
    const int e = (blk - NB_CVTX - NB_CVTW) * 256 + t;
    if (e < ETOT) {
      int dst = (e < Ev) ? ei[Ev + e] : (e - Ev);
      int src = (e < Ev) ? ei[e] : (e - Ev);
      int pos = atomicAdd(&cnt[dst], 1);
      csrp[dst * DEGMAX + pos] = src;  // store src directly
    }
  }
}

// ------ GEMM + fused attention dots: 2-PHASE double-buffered LDS -----------
// 256x128 tile, BK=64, 8 waves, 240 blocks (~1/CU, XCD-swizzled A reuse).
// STAGE(k+1) into buf^1 issued BEFORE computing buf -> loads overlap MFMA;
// ONE barrier per K-step (compiler's auto vmcnt(0)+lgkmcnt(0) drain at
// __syncthreads waits on loads that had the whole compute phase in flight).
#define STAGE(bi, kk)                                                          \
  {                                                                            \
    _Pragma("unroll")                                                          \
    for (int i = 0; i < 4; ++i) {                                              \
      const int r = i * 64 + rs;                                               \
      GLD16(A + (size_t)(bm + r) * Cv + (kk) + sl * 8, &As[bi][t * 8 + i * 4096]); \
    }                                                                          \
    _Pragma("unroll")                                                          \
    for (int i = 0; i < 2; ++i) {                                              \
      const int r = i * 64 + rs;                                               \
      GLD16(Bt + (size_t)(bn + r) * Cv + (kk) + sl * 8, &Bs[bi][t * 8 + i * 4096]); \
    }                                                                          \
  }

__global__ __launch_bounds__(512) void k_gemm_mfma(const unsigned short* __restrict__ A,
                                                   const unsigned short* __restrict__ Bt,
                                                   unsigned short* __restrict__ C,
                                                   const float* __restrict__ att_src,
                                                   const float* __restrict__ att_dst,
                                                   float* __restrict__ asrc,
                                                   float* __restrict__ adst) {
  __shared__ unsigned short As[2][256 * 64];
  __shared__ unsigned short Bs[2][128 * 64];
  const int l0 = blockIdx.x;
  const int xcd = l0 & 7, j = l0 >> 3;        // j < 30
  const int bm = (xcd + 8 * (j / 6)) * 256;   // M-block pinned to xcd
  const int bn = (j % 6) * 128;
  const int t = threadIdx.x;
  const int w = t >> 6, l = t & 63;
  const int wr = w >> 1, wc = w & 1;          // 4 x 2 wave grid
  const int g = l >> 4, li = l & 15;
  f32x4 acc[4][4] = {};

  const int rs = t >> 3;              // staging row within 64-row issue (0..63)
  const int sl = (t & 7) ^ (rs & 7);  // pre-swizzled logical slot for source

  STAGE(0, 0);
  __syncthreads();
  int cur = 0;
#pragma unroll 1
  for (int step = 0; step < Cv / 64; ++step) {
    if (step + 1 < Cv / 64) STAGE(cur ^ 1, (step + 1) * 64);
#pragma unroll
    for (int ks = 0; ks < 2; ++ks) {
      bf16x8 a[4], b[4];
#pragma unroll
      for (int mi = 0; mi < 4; ++mi) {
        const int row = wr * 64 + mi * 16 + li;
        const int slot = (ks * 4 + g) ^ (row & 7);
        a[mi] = *(const bf16x8*)&As[cur][row * 64 + slot * 8];
      }
#pragma unroll
      for (int nj = 0; nj < 4; ++nj) {
        const int row = wc * 64 + nj * 16 + li;
        const int slot = (ks * 4 + g) ^ (row & 7);
        b[nj] = *(const bf16x8*)&Bs[cur][row * 64 + slot * 8];
      }
#pragma unroll
      for (int mi = 0; mi < 4; ++mi)
#pragma unroll
        for (int nj = 0; nj < 4; ++nj)
          acc[mi][nj] = __builtin_amdgcn_mfma_f32_16x16x32_bf16(a[mi], b[nj], acc[mi][nj], 0, 0, 0);
    }
    __syncthreads();  // drains vmcnt(0): next buffer staged; reads of cur done
    cur ^= 1;
  }
  // C/D layout: col = lane&15, row = (lane>>4)*4 + reg (m89-verified)
#pragma unroll
  for (int mi = 0; mi < 4; ++mi) {
#pragma unroll
    for (int nj = 0; nj < 4; ++nj) {
      const int col = bn + wc * 64 + nj * 16 + li;
#pragma unroll
      for (int r4 = 0; r4 < 4; ++r4) {
        const int row = bm + wr * 64 + mi * 16 + g * 4 + r4;
        C[(size_t)row * HD + col] = f2b(acc[mi][nj][r4]);
      }
    }
  }
  // fused attention-dot epilogue: head covered by this wave's 64 cols
  {
    const int head = (bn >> 6) + wc;
    float aS[4], aD[4];
#pragma unroll
    for (int nj = 0; nj < 4; ++nj) {
      aS[nj] = att_src[head * Dv + nj * 16 + li];
      aD[nj] = att_dst[head * Dv + nj * 16 + li];
    }
#pragma unroll
    for (int mi = 0; mi < 4; ++mi) {
#pragma unroll
      for (int r4 = 0; r4 < 4; ++r4) {
        float vs = 0.f, vd = 0.f;
#pragma unroll
        for (int nj = 0; nj < 4; ++nj) {
          const float hv = acc[mi][nj][r4];
          vs = fmaf(hv, aS[nj], vs);
          vd = fmaf(hv, aD[nj], vd);
        }
        vs += __shfl_xor(vs, 1); vd += __shfl_xor(vd, 1);
        vs += __shfl_xor(vs, 2); vd += __shfl_xor(vd, 2);
        vs += __shfl_xor(vs, 4); vd += __shfl_xor(vd, 4);
        vs += __shfl_xor(vs, 8); vd += __shfl_xor(vd, 8);
        const int row = bm + wr * 64 + mi * 16 + g * 4 + r4;
        if (li == 0 && row < Mv) {
          asrc[(size_t)row * Hv + head] = vs;
          adst[(size_t)row * Hv + head] = vd;
        }
      }
    }
  }
}

// ------- fused softmax + aggregation: block per (b, n-pair) ----------------
// R15 version (best measured: 50.4us). 192 threads = 2 nodes x 96 lanes.
#define EDGE_FMA(c, wv)                                              \
  {                                                                  \
    acc[0] = fmaf(wv, __uint_as_float((c).x << 16), acc[0]);         \
    acc[1] = fmaf(wv, __uint_as_float((c).x & 0xFFFF0000u), acc[1]); \
    acc[2] = fmaf(wv, __uint_as_float((c).y << 16), acc[2]);         \
    acc[3] = fmaf(wv, __uint_as_float((c).y & 0xFFFF0000u), acc[3]); \
    acc[4] = fmaf(wv, __uint_as_float((c).z << 16), acc[4]);         \
    acc[5] = fmaf(wv, __uint_as_float((c).z & 0xFFFF0000u), acc[5]); \
    acc[6] = fmaf(wv, __uint_as_float((c).w << 16), acc[6]);         \
    acc[7] = fmaf(wv, __uint_as_float((c).w & 0xFFFF0000u), acc[7]); \
  }

__global__ __launch_bounds__(192) void k_agg(const unsigned short* __restrict__ h2,
                                             const int* __restrict__ cnt,
                                             const int* __restrict__ csrp,
                                             const float* __restrict__ asrc,
                                             const float* __restrict__ adst,
                                             const float* __restrict__ bias,
                                             float* __restrict__ out) {
  const int xcd = blockIdx.x & 7;
  const int idx = blockIdx.x >> 3;        // 0..624
  const int b = xcd >> 2;
  const int pair = (xcd & 3) * 625 + idx; // 0..2499
  const int n0 = pair * 2;                // block handles n0, n0+1
  const int t = threadIdx.x;
  __shared__ int s_src[2][DEGPAD];
  __shared__ float s_w[2][Hv][DEGW];
  __shared__ float s_inv[2][16];
  const int d0 = cnt[n0], d1 = cnt[n0 + 1];  // <= DEGMAX
  for (int i = t; i < 2 * DEGPAD; i += 192) {
    const int jn = i >= DEGPAD;
    const int ii = i - jn * DEGPAD;
    const int dd = jn ? d1 : d0;
    int sv = 0;
    if (ii < dd) sv = csrp[(n0 + jn) * DEGMAX + ii];
    s_src[jn][ii] = sv;  // pad with row 0 (safe to load, weight = 0)
  }
  __syncthreads();
  // Phase A: (node jn, head-quad q, slot): one f32x4 asrc load serves 4 heads
  {
    const int jn = t / 96, rq = t % 96;
    const int q = rq >> 5, slot = rq & 31;   // q = head quad (0..2)
    const int deg = jn ? d1 : d0;
    const int degp = (deg + 7) & ~7;
    const f32x4 adv4 = *(const f32x4*)&adst[((size_t)b * Nv + n0 + jn) * Hv + q * 4];
    f32x4 ps = {0.f, 0.f, 0.f, 0.f};
    for (int i = slot; i < deg; i += 32) {
      const int src = s_src[jn][i];
      const f32x4 as4 = *(const f32x4*)&asrc[((size_t)b * Nv + src) * Hv + q * 4];
#pragma unroll
      for (int jq = 0; jq < 4; ++jq) {
        float v = as4[jq] + adv4[jq];
        v = fmaxf(v, NEG * v);      // leaky_relu
        float ex = __expf(v);
        s_w[jn][q * 4 + jq][i] = ex;
        ps[jq] += ex;
      }
    }
    for (int i = deg + slot; i < degp; i += 32) {
#pragma unroll
      for (int jq = 0; jq < 4; ++jq) s_w[jn][q * 4 + jq][i] = 0.f;
    }
#pragma unroll
    for (int jq = 0; jq < 4; ++jq) {
      ps[jq] += __shfl_xor(ps[jq], 1);
      ps[jq] += __shfl_xor(ps[jq], 2);
      ps[jq] += __shfl_xor(ps[jq], 4);
      ps[jq] += __shfl_xor(ps[jq], 8);
      ps[jq] += __shfl_xor(ps[jq], 16);
    }
    if (slot == 0) {
      f32x4 inv;
#pragma unroll
      for (int jq = 0; jq < 4; ++jq) inv[jq] = 1.0f / (ps[jq] + 1e-16f);
      *(f32x4*)&s_inv[jn][q * 4] = inv;
    }
  }
  __syncthreads();
  // Phase B: node jn, lane tl owns dims [8tl, 8tl+8); no guards (0-padded w)
  const int jn = t >= 96;
  const int tl = t - jn * 96;
  const int hl = tl >> 3;  // head
  const int degp = ((jn ? d1 : d0) + 7) & ~7;
  float acc[8] = {};
  const unsigned short* hrow = h2 + (size_t)b * Nv * HD + tl * 8;
  uint4 cA[4], cB[4];
#pragma unroll
  for (int k = 0; k < 4; ++k)
    cA[k] = *(const uint4*)(hrow + (size_t)s_src[jn][k] * HD);
  for (int base = 0; base < degp; base += 8) {
#pragma unroll
    for (int k = 0; k < 4; ++k)
      cB[k] = *(const uint4*)(hrow + (size_t)s_src[jn][base + 4 + k] * HD);
    {
      const f32x4 w4 = *(const f32x4*)&s_w[jn][hl][base];
      EDGE_FMA(cA[0], w4[0]); EDGE_FMA(cA[1], w4[1]);
      EDGE_FMA(cA[2], w4[2]); EDGE_FMA(cA[3], w4[3]);
    }
#pragma unroll
    for (int k = 0; k < 4; ++k)
      cA[k] = *(const uint4*)(hrow + (size_t)s_src[jn][base + 8 + k] * HD);  // max 131 < DEGPAD
    {
      const f32x4 w4 = *(const f32x4*)&s_w[jn][hl][base + 4];
      EDGE_FMA(cB[0], w4[0]); EDGE_FMA(cB[1], w4[1]);
      EDGE_FMA(cB[2], w4[2]); EDGE_FMA(cB[3], w4[3]);
    }
  }
  const float invh = s_inv[jn][hl];
  const int od = tl * 8;
  float4 o0, o1;
  o0.x = fmaf(acc[0], invh, bias[od + 0]);
  o0.y = fmaf(acc[1], invh, bias[od + 1]);
  o0.z = fmaf(acc[2], invh, bias[od + 2]);
  o0.w = fmaf(acc[3], invh, bias[od + 3]);
  o1.x = fmaf(acc[4], invh, bias[od + 4]);
  o1.y = fmaf(acc[5], invh, bias[od + 5]);
  o1.z = fmaf(acc[6], invh, bias[od + 6]);
  o1.w = fmaf(acc[7], invh, bias[od + 7]);
  float* op = out + ((size_t)b * Nv + n0 + jn) * HD + od;
  *(float4*)op = o0;
  *(float4*)(op + 4) = o1;
}

extern "C" void kernel_launch(void* const* d_in, const int* in_sizes, int n_in,
                              void* d_out, int out_size, void* d_ws, size_t ws_size,
                              hipStream_t stream) {
  const float* x = (const float*)d_in[0];
  const float* W = (const float*)d_in[1];
  const float* att_src = (const float*)d_in[2];
  const float* att_dst = (const float*)d_in[3];
  const float* bias = (const float*)d_in[4];
  const int* ei = (const int*)d_in[5];
  float* out = (float*)d_out;

  // workspace layout
  unsigned short* h2 = (unsigned short*)d_ws;            // MPAD*768 bf16
  unsigned short* xbf = h2 + (size_t)MPAD * HD;          // MPAD*768 bf16
  unsigned short* wt = xbf + (size_t)MPAD * HD;          // 768*768 bf16
  float* asrc = (float*)(wt + (size_t)HD * Cv);          // 120,000 f32
  float* adst = asrc + (size_t)Bv * Nv * Hv;             // 120,000 f32
  int* cnt = (int*)(adst + (size_t)Bv * Nv * Hv);        // Nv (count AND cursor)
  int* csrp = cnt + Nv;                                  // Nv*DEGMAX padded CSR

  hipMemsetAsync(cnt, 0, sizeof(int) * Nv, stream);

  k_prep<<<NB_CVTX + NB_CVTW + NB_CNT, 256, 0, stream>>>(x, xbf, W, wt, ei, cnt, csrp);
  k_gemm_mfma<<<240, 512, 0, stream>>>(xbf, wt, h2, att_src, att_dst, asrc, adst);
  k_agg<<<Bv * Nv / 2, 192, 0, stream>>>(h2, cnt, csrp, asrc, adst, bias, out);
}

// Round 17
// 97.298 us; speedup vs baseline: 1.4735x; 1.0024x over previous
//
#include <hip/hip_runtime.h>

#define Bv 2
#define Nv 5000
#define Cv 768
#define Hv 12
#define Dv 64
#define Ev 160000
#define ETOT (Ev + Nv)   // 165000 (edges + self loops)
#define HD 768
#define NEG 0.2f
#define Mv (Bv * Nv)     // 10000
#define MPAD 10240       // 80 * 128
#define DEGMAX 128       // max in-degree incl. self-loop; Poisson(33) tail -> safe
#define DEGPAD 136       // staging pad so 4-deep prefetch can overread (max idx 131)
#define DEGW 132         // s_w edge stride: 4*33 keeps 16B align, spreads banks

typedef __bf16 bf16x8 __attribute__((ext_vector_type(8)));
typedef float f32x4 __attribute__((ext_vector_type(4)));

// direct-to-LDS 16B async copy
#define GLD16(gsrc, ldst)                                                      \
  __builtin_amdgcn_global_load_lds(                                            \
      (const __attribute__((address_space(1))) unsigned int*)(gsrc),           \
      (__attribute__((address_space(3))) unsigned int*)(ldst), 16, 0, 0)

// f32 -> bf16 round-to-nearest-even
__device__ __forceinline__ unsigned short f2b(float f) {
  unsigned u = __float_as_uint(f);
  return (unsigned short)((u + 0x7FFFu + ((u >> 16) & 1u)) >> 16);
}

// ---- merged prep: cvt_x | cvt_wt | count+scatter (padded dense CSR) -------
#define NB_CVTX 3840   // MPAD*HD/8/256
#define NB_CVTW 576    // (768/32)*(768/32)
#define NB_CNT  645    // ceil(ETOT/256)
__global__ __launch_bounds__(256) void k_prep(const float* __restrict__ x,
                                              unsigned short* __restrict__ xb,
                                              const float* __restrict__ W,
                                              unsigned short* __restrict__ Wt,
                                              const int* __restrict__ ei,
                                              int* __restrict__ cnt,
                                              int* __restrict__ csrp) {
  const int blk = blockIdx.x;
  const int t = threadIdx.x;
  if (blk < NB_CVTX) {
    size_t i = ((size_t)blk * 256 + t) * 8;
    unsigned short o[8];
    if (i < (size_t)Mv * Cv) {
      float4 v0 = *(const float4*)(x + i);
      float4 v1 = *(const float4*)(x + i + 4);
      o[0] = f2b(v0.x); o[1] = f2b(v0.y); o[2] = f2b(v0.z); o[3] = f2b(v0.w);
      o[4] = f2b(v1.x); o[5] = f2b(v1.y); o[6] = f2b(v1.z); o[7] = f2b(v1.w);
    } else {
      for (int j = 0; j < 8; ++j) o[j] = 0;
    }
    *(uint4*)(xb + i) = *(const uint4*)o;
  } else if (blk < NB_CVTX + NB_CVTW) {
    __shared__ float s[32][33];
    const int bw = blk - NB_CVTX;
    const int n0 = (bw % 24) * 32, k0 = (bw / 24) * 32;
    const int tx = t & 31, ty = t >> 5;  // 32 x 8
#pragma unroll
    for (int i = 0; i < 4; ++i)
      s[ty + i * 8][tx] = W[(size_t)(k0 + ty + i * 8) * HD + n0 + tx];
    __syncthreads();
#pragma unroll
    for (int i = 0; i < 4; ++i)
      Wt[(size_t)(n0 + ty + i * 8) * Cv + k0 + tx] = f2b(s[tx][ty + i * 8]);
  } else {
    const int e = (blk - NB_CVTX - NB_CVTW) * 256 + t;
    if (e < ETOT) {
      int dst = (e < Ev) ? ei[Ev + e] : (e - Ev);
      int src = (e < Ev) ? ei[e] : (e - Ev);
      int pos = atomicAdd(&cnt[dst], 1);
      csrp[dst * DEGMAX + pos] = src;  // store src directly
    }
  }
}

// ------ GEMM + fused attention dots: m97 structure (128x128, 4 waves) ------
// 256 threads, single-buffer, 2 barriers/K-step; VGPR ~164 -> 3 blocks/CU,
// so co-resident blocks hide the staging drain (m114 wave-overlap).
// Grid 480 = 80 M-blocks x 6 N-tiles, XCD-swizzled: one M-block's 6 N-tiles
// share an XCD -> A panel read from HBM once, then L2.
__global__ __launch_bounds__(256) void k_gemm_mfma(const unsigned short* __restrict__ A,
                                                   const unsigned short* __restrict__ Bt,
                                                   unsigned short* __restrict__ C,
                                                   const float* __restrict__ att_src,
                                                   const float* __restrict__ att_dst,
                                                   float* __restrict__ asrc,
                                                   float* __restrict__ adst) {
  __shared__ unsigned short As[128 * 64];
  __shared__ unsigned short Bs[128 * 64];
  const int l0 = blockIdx.x;
  const int xcd = l0 & 7, j = l0 >> 3;        // j < 60
  const int bm = (xcd + 8 * (j / 6)) * 128;   // M-block pinned to xcd (0..79)
  const int bn = (j % 6) * 128;
  const int t = threadIdx.x;
  const int w = t >> 6, l = t & 63;
  const int wr = w >> 1, wc = w & 1;          // 2 x 2 wave grid
  const int g = l >> 4, li = l & 15;
  f32x4 acc[4][4] = {};

  const int rs = t >> 3;              // staging row within 32-row issue (0..31)
  const int sl = (t & 7) ^ (rs & 7);  // pre-swizzled logical slot for source

  for (int k0 = 0; k0 < Cv; k0 += 64) {
#pragma unroll
    for (int i = 0; i < 4; ++i) {
      const int r = i * 32 + rs;
      GLD16(A + (size_t)(bm + r) * Cv + k0 + sl * 8, &As[t * 8 + i * 2048]);
      GLD16(Bt + (size_t)(bn + r) * Cv + k0 + sl * 8, &Bs[t * 8 + i * 2048]);
    }
    __syncthreads();  // drains vmcnt(0); other resident blocks cover the stall
#pragma unroll
    for (int ks = 0; ks < 2; ++ks) {
      bf16x8 a[4], b[4];
#pragma unroll
      for (int mi = 0; mi < 4; ++mi) {
        const int row = wr * 64 + mi * 16 + li;
        const int slot = (ks * 4 + g) ^ (row & 7);
        a[mi] = *(const bf16x8*)&As[row * 64 + slot * 8];
      }
#pragma unroll
      for (int nj = 0; nj < 4; ++nj) {
        const int row = wc * 64 + nj * 16 + li;
        const int slot = (ks * 4 + g) ^ (row & 7);
        b[nj] = *(const bf16x8*)&Bs[row * 64 + slot * 8];
      }
#pragma unroll
      for (int mi = 0; mi < 4; ++mi)
#pragma unroll
        for (int nj = 0; nj < 4; ++nj)
          acc[mi][nj] = __builtin_amdgcn_mfma_f32_16x16x32_bf16(a[mi], b[nj], acc[mi][nj], 0, 0, 0);
    }
    __syncthreads();  // protect LDS before next stage
  }
  // C/D layout: col = lane&15, row = (lane>>4)*4 + reg (m89-verified)
#pragma unroll
  for (int mi = 0; mi < 4; ++mi) {
#pragma unroll
    for (int nj = 0; nj < 4; ++nj) {
      const int col = bn + wc * 64 + nj * 16 + li;
#pragma unroll
      for (int r4 = 0; r4 < 4; ++r4) {
        const int row = bm + wr * 64 + mi * 16 + g * 4 + r4;
        C[(size_t)row * HD + col] = f2b(acc[mi][nj][r4]);
      }
    }
  }
  // fused attention-dot epilogue: head covered by this wave's 64 cols
  {
    const int head = (bn >> 6) + wc;  // 2*(j%6) + wc
    float aS[4], aD[4];
#pragma unroll
    for (int nj = 0; nj < 4; ++nj) {
      aS[nj] = att_src[head * Dv + nj * 16 + li];
      aD[nj] = att_dst[head * Dv + nj * 16 + li];
    }
#pragma unroll
    for (int mi = 0; mi < 4; ++mi) {
#pragma unroll
      for (int r4 = 0; r4 < 4; ++r4) {
        float vs = 0.f, vd = 0.f;
#pragma unroll
        for (int nj = 0; nj < 4; ++nj) {
          const float hv = acc[mi][nj][r4];
          vs = fmaf(hv, aS[nj], vs);
          vd = fmaf(hv, aD[nj], vd);
        }
        vs += __shfl_xor(vs, 1); vd += __shfl_xor(vd, 1);
        vs += __shfl_xor(vs, 2); vd += __shfl_xor(vd, 2);
        vs += __shfl_xor(vs, 4); vd += __shfl_xor(vd, 4);
        vs += __shfl_xor(vs, 8); vd += __shfl_xor(vd, 8);
        const int row = bm + wr * 64 + mi * 16 + g * 4 + r4;
        if (li == 0 && row < Mv) {
          asrc[(size_t)row * Hv + head] = vs;
          adst[(size_t)row * Hv + head] = vd;
        }
      }
    }
  }
}

// ------- fused softmax + aggregation: block per (b, n-pair) ----------------
// R15 version (best measured: 50.4us). 192 threads = 2 nodes x 96 lanes.
#define EDGE_FMA(c, wv)                                              \
  {                                                                  \
    acc[0] = fmaf(wv, __uint_as_float((c).x << 16), acc[0]);         \
    acc[1] = fmaf(wv, __uint_as_float((c).x & 0xFFFF0000u), acc[1]); \
    acc[2] = fmaf(wv, __uint_as_float((c).y << 16), acc[2]);         \
    acc[3] = fmaf(wv, __uint_as_float((c).y & 0xFFFF0000u), acc[3]); \
    acc[4] = fmaf(wv, __uint_as_float((c).z << 16), acc[4]);         \
    acc[5] = fmaf(wv, __uint_as_float((c).z & 0xFFFF0000u), acc[5]); \
    acc[6] = fmaf(wv, __uint_as_float((c).w << 16), acc[6]);         \
    acc[7] = fmaf(wv, __uint_as_float((c).w & 0xFFFF0000u), acc[7]); \
  }

__global__ __launch_bounds__(192) void k_agg(const unsigned short* __restrict__ h2,
                                             const int* __restrict__ cnt,
                                             const int* __restrict__ csrp,
                                             const float* __restrict__ asrc,
                                             const float* __restrict__ adst,
                                             const float* __restrict__ bias,
                                             float* __restrict__ out) {
  const int xcd = blockIdx.x & 7;
  const int idx = blockIdx.x >> 3;        // 0..624
  const int b = xcd >> 2;
  const int pair = (xcd & 3) * 625 + idx; // 0..2499
  const int n0 = pair * 2;                // block handles n0, n0+1
  const int t = threadIdx.x;
  __shared__ int s_src[2][DEGPAD];
  __shared__ float s_w[2][Hv][DEGW];
  __shared__ float s_inv[2][16];
  const int d0 = cnt[n0], d1 = cnt[n0 + 1];  // <= DEGMAX
  for (int i = t; i < 2 * DEGPAD; i += 192) {
    const int jn = i >= DEGPAD;
    const int ii = i - jn * DEGPAD;
    const int dd = jn ? d1 : d0;
    int sv = 0;
    if (ii < dd) sv = csrp[(n0 + jn) * DEGMAX + ii];
    s_src[jn][ii] = sv;  // pad with row 0 (safe to load, weight = 0)
  }
  __syncthreads();
  // Phase A: (node jn, head-quad q, slot): one f32x4 asrc load serves 4 heads
  {
    const int jn = t / 96, rq = t % 96;
    const int q = rq >> 5, slot = rq & 31;   // q = head quad (0..2)
    const int deg = jn ? d1 : d0;
    const int degp = (deg + 7) & ~7;
    const f32x4 adv4 = *(const f32x4*)&adst[((size_t)b * Nv + n0 + jn) * Hv + q * 4];
    f32x4 ps = {0.f, 0.f, 0.f, 0.f};
    for (int i = slot; i < deg; i += 32) {
      const int src = s_src[jn][i];
      const f32x4 as4 = *(const f32x4*)&asrc[((size_t)b * Nv + src) * Hv + q * 4];
#pragma unroll
      for (int jq = 0; jq < 4; ++jq) {
        float v = as4[jq] + adv4[jq];
        v = fmaxf(v, NEG * v);      // leaky_relu
        float ex = __expf(v);
        s_w[jn][q * 4 + jq][i] = ex;
        ps[jq] += ex;
      }
    }
    for (int i = deg + slot; i < degp; i += 32) {
#pragma unroll
      for (int jq = 0; jq < 4; ++jq) s_w[jn][q * 4 + jq][i] = 0.f;
    }
#pragma unroll
    for (int jq = 0; jq < 4; ++jq) {
      ps[jq] += __shfl_xor(ps[jq], 1);
      ps[jq] += __shfl_xor(ps[jq], 2);
      ps[jq] += __shfl_xor(ps[jq], 4);
      ps[jq] += __shfl_xor(ps[jq], 8);
      ps[jq] += __shfl_xor(ps[jq], 16);
    }
    if (slot == 0) {
      f32x4 inv;
#pragma unroll
      for (int jq = 0; jq < 4; ++jq) inv[jq] = 1.0f / (ps[jq] + 1e-16f);
      *(f32x4*)&s_inv[jn][q * 4] = inv;
    }
  }
  __syncthreads();
  // Phase B: node jn, lane tl owns dims [8tl, 8tl+8); no guards (0-padded w)
  const int jn = t >= 96;
  const int tl = t - jn * 96;
  const int hl = tl >> 3;  // head
  const int degp = ((jn ? d1 : d0) + 7) & ~7;
  float acc[8] = {};
  const unsigned short* hrow = h2 + (size_t)b * Nv * HD + tl * 8;
  uint4 cA[4], cB[4];
#pragma unroll
  for (int k = 0; k < 4; ++k)
    cA[k] = *(const uint4*)(hrow + (size_t)s_src[jn][k] * HD);
  for (int base = 0; base < degp; base += 8) {
#pragma unroll
    for (int k = 0; k < 4; ++k)
      cB[k] = *(const uint4*)(hrow + (size_t)s_src[jn][base + 4 + k] * HD);
    {
      const f32x4 w4 = *(const f32x4*)&s_w[jn][hl][base];
      EDGE_FMA(cA[0], w4[0]); EDGE_FMA(cA[1], w4[1]);
      EDGE_FMA(cA[2], w4[2]); EDGE_FMA(cA[3], w4[3]);
    }
#pragma unroll
    for (int k = 0; k < 4; ++k)
      cA[k] = *(const uint4*)(hrow + (size_t)s_src[jn][base + 8 + k] * HD);  // max 131 < DEGPAD
    {
      const f32x4 w4 = *(const f32x4*)&s_w[jn][hl][base + 4];
      EDGE_FMA(cB[0], w4[0]); EDGE_FMA(cB[1], w4[1]);
      EDGE_FMA(cB[2], w4[2]); EDGE_FMA(cB[3], w4[3]);
    }
  }
  const float invh = s_inv[jn][hl];
  const int od = tl * 8;
  float4 o0, o1;
  o0.x = fmaf(acc[0], invh, bias[od + 0]);
  o0.y = fmaf(acc[1], invh, bias[od + 1]);
  o0.z = fmaf(acc[2], invh, bias[od + 2]);
  o0.w = fmaf(acc[3], invh, bias[od + 3]);
  o1.x = fmaf(acc[4], invh, bias[od + 4]);
  o1.y = fmaf(acc[5], invh, bias[od + 5]);
  o1.z = fmaf(acc[6], invh, bias[od + 6]);
  o1.w = fmaf(acc[7], invh, bias[od + 7]);
  float* op = out + ((size_t)b * Nv + n0 + jn) * HD + od;
  *(float4*)op = o0;
  *(float4*)(op + 4) = o1;
}

extern "C" void kernel_launch(void* const* d_in, const int* in_sizes, int n_in,
                              void* d_out, int out_size, void* d_ws, size_t ws_size,
                              hipStream_t stream) {
  const float* x = (const float*)d_in[0];
  const float* W = (const float*)d_in[1];
  const float* att_src = (const float*)d_in[2];
  const float* att_dst = (const float*)d_in[3];
  const float* bias = (const float*)d_in[4];
  const int* ei = (const int*)d_in[5];
  float* out = (float*)d_out;

  // workspace layout
  unsigned short* h2 = (unsigned short*)d_ws;            // MPAD*768 bf16
  unsigned short* xbf = h2 + (size_t)MPAD * HD;          // MPAD*768 bf16
  unsigned short* wt = xbf + (size_t)MPAD * HD;          // 768*768 bf16
  float* asrc = (float*)(wt + (size_t)HD * Cv);          // 120,000 f32
  float* adst = asrc + (size_t)Bv * Nv * Hv;             // 120,000 f32
  int* cnt = (int*)(adst + (size_t)Bv * Nv * Hv);        // Nv (count AND cursor)
  int* csrp = cnt + Nv;                                  // Nv*DEGMAX padded CSR

  hipMemsetAsync(cnt, 0, sizeof(int) * Nv, stream);

  k_prep<<<NB_CVTX + NB_CVTW + NB_CNT, 256, 0, stream>>>(x, xbf, W, wt, ei, cnt, csrp);
  k_gemm_mfma<<<480, 256, 0, stream>>>(xbf, wt, h2, att_src, att_dst, asrc, adst);
  k_agg<<<Bv * Nv / 2, 192, 0, stream>>>(h2, cnt, csrp, asrc, adst, bias, out);
}

// Round 18
// 94.041 us; speedup vs baseline: 1.5245x; 1.0346x over previous
//
#include <hip/hip_runtime.h>

#define Bv 2
#define Nv 5000
#define Cv 768
#define Hv 12
#define Dv 64
#define Ev 160000
#define ETOT (Ev + Nv)   // 165000 (edges + self loops)
#define HD 768
#define NEG 0.2f
#define Mv (Bv * Nv)     // 10000
#define MPAD 10240       // 80 * 128
#define DEGMAX 128       // max in-degree incl. self-loop; Poisson(33) tail -> safe
#define DEGPAD 136       // staging pad so 4-deep prefetch can overread (max idx 131)
#define DEGW 132         // s_w edge stride: 4*33 keeps 16B align, spreads banks

typedef __bf16 bf16x8 __attribute__((ext_vector_type(8)));
typedef float f32x4 __attribute__((ext_vector_type(4)));

// direct-to-LDS 16B async copy
#define GLD16(gsrc, ldst)                                                      \
  __builtin_amdgcn_global_load_lds(                                            \
      (const __attribute__((address_space(1))) unsigned int*)(gsrc),           \
      (__attribute__((address_space(3))) unsigned int*)(ldst), 16, 0, 0)

// f32 -> bf16 round-to-nearest-even
__device__ __forceinline__ unsigned short f2b(float f) {
  unsigned u = __float_as_uint(f);
  return (unsigned short)((u + 0x7FFFu + ((u >> 16) & 1u)) >> 16);
}

// ---- merged prep: cvt_wt | count+scatter (padded dense CSR) ---------------
// (cvt_x is gone: GEMM now converts x during A-staging.)
#define NB_CVTW 576    // (768/32)*(768/32)
#define NB_CNT  645    // ceil(ETOT/256)
__global__ __launch_bounds__(256) void k_prep(const float* __restrict__ W,
                                              unsigned short* __restrict__ Wt,
                                              const int* __restrict__ ei,
                                              int* __restrict__ cnt,
                                              int* __restrict__ csrp) {
  const int blk = blockIdx.x;
  const int t = threadIdx.x;
  if (blk < NB_CVTW) {
    __shared__ float s[32][33];
    const int n0 = (blk % 24) * 32, k0 = (blk / 24) * 32;
    const int tx = t & 31, ty = t >> 5;  // 32 x 8
#pragma unroll
    for (int i = 0; i < 4; ++i)
      s[ty + i * 8][tx] = W[(size_t)(k0 + ty + i * 8) * HD + n0 + tx];
    __syncthreads();
#pragma unroll
    for (int i = 0; i < 4; ++i)
      Wt[(size_t)(n0 + ty + i * 8) * Cv + k0 + tx] = f2b(s[tx][ty + i * 8]);
  } else {
    const int e = (blk - NB_CVTW) * 256 + t;
    if (e < ETOT) {
      int dst = (e < Ev) ? ei[Ev + e] : (e - Ev);
      int src = (e < Ev) ? ei[e] : (e - Ev);
      int pos = atomicAdd(&cnt[dst], 1);
      csrp[dst * DEGMAX + pos] = src;  // store src directly
    }
  }
}

// ------ GEMM (f32 x input, fused cvt) + attention-dot epilogue -------------
// m97 structure: 128x128 tile, 4 waves, 256 threads, single-buffer.
// A staged from f32 x: load 2xfloat4 -> cvt -> ds_write_b128 into the SAME
// XOR-swizzled layout (dest slot = ssl^(row&7); read side unchanged).
// B staged via global_load_lds from pre-converted wt. Grid 480, XCD-swizzled.
__global__ __launch_bounds__(256) void k_gemm_mfma(const float* __restrict__ Ax,
                                                   const unsigned short* __restrict__ Bt,
                                                   unsigned short* __restrict__ C,
                                                   const float* __restrict__ att_src,
                                                   const float* __restrict__ att_dst,
                                                   float* __restrict__ asrc,
                                                   float* __restrict__ adst) {
  __shared__ unsigned short As[128 * 64];
  __shared__ unsigned short Bs[128 * 64];
  const int l0 = blockIdx.x;
  const int xcd = l0 & 7, j = l0 >> 3;        // j < 60
  const int bm = (xcd + 8 * (j / 6)) * 128;   // M-block pinned to xcd (0..79)
  const int bn = (j % 6) * 128;
  const int t = threadIdx.x;
  const int w = t >> 6, l = t & 63;
  const int wr = w >> 1, wc = w & 1;          // 2 x 2 wave grid
  const int g = l >> 4, li = l & 15;
  f32x4 acc[4][4] = {};

  const int rs = t >> 3;              // staging row within 32-row issue (0..31)
  const int ssl = t & 7;              // logical k-slot (A reg-staging)
  const int sl = ssl ^ (rs & 7);      // pre-swizzled slot for B's linear GLD

  for (int k0 = 0; k0 < Cv; k0 += 64) {
    // B: async direct-to-LDS (linear dest, pre-swizzled source slot)
#pragma unroll
    for (int i = 0; i < 4; ++i) {
      const int r = i * 32 + rs;
      GLD16(Bt + (size_t)(bn + r) * Cv + k0 + sl * 8, &Bs[t * 8 + i * 2048]);
    }
    // A: f32 load + in-register cvt + swizzled ds_write
    float4 av[4][2];
#pragma unroll
    for (int i = 0; i < 4; ++i) {
      const int grow = bm + i * 32 + rs;
      if (grow < Mv) {
        const float* ap = Ax + (size_t)grow * Cv + k0 + ssl * 8;
        av[i][0] = *(const float4*)ap;
        av[i][1] = *(const float4*)(ap + 4);
      } else {
        av[i][0] = make_float4(0.f, 0.f, 0.f, 0.f);
        av[i][1] = av[i][0];
      }
    }
#pragma unroll
    for (int i = 0; i < 4; ++i) {
      const int r = i * 32 + rs;
      unsigned short o[8];
      o[0] = f2b(av[i][0].x); o[1] = f2b(av[i][0].y);
      o[2] = f2b(av[i][0].z); o[3] = f2b(av[i][0].w);
      o[4] = f2b(av[i][1].x); o[5] = f2b(av[i][1].y);
      o[6] = f2b(av[i][1].z); o[7] = f2b(av[i][1].w);
      const int ds = ssl ^ (r & 7);
      *(uint4*)&As[r * 64 + ds * 8] = *(const uint4*)o;
    }
    __syncthreads();  // waits ds_write (lgkm) + GLD16 (vmcnt); co-resident blocks cover
#pragma unroll
    for (int ks = 0; ks < 2; ++ks) {
      bf16x8 a[4], b[4];
#pragma unroll
      for (int mi = 0; mi < 4; ++mi) {
        const int row = wr * 64 + mi * 16 + li;
        const int slot = (ks * 4 + g) ^ (row & 7);
        a[mi] = *(const bf16x8*)&As[row * 64 + slot * 8];
      }
#pragma unroll
      for (int nj = 0; nj < 4; ++nj) {
        const int row = wc * 64 + nj * 16 + li;
        const int slot = (ks * 4 + g) ^ (row & 7);
        b[nj] = *(const bf16x8*)&Bs[row * 64 + slot * 8];
      }
#pragma unroll
      for (int mi = 0; mi < 4; ++mi)
#pragma unroll
        for (int nj = 0; nj < 4; ++nj)
          acc[mi][nj] = __builtin_amdgcn_mfma_f32_16x16x32_bf16(a[mi], b[nj], acc[mi][nj], 0, 0, 0);
    }
    __syncthreads();  // protect LDS before next stage
  }
  // C/D layout: col = lane&15, row = (lane>>4)*4 + reg (m89-verified)
#pragma unroll
  for (int mi = 0; mi < 4; ++mi) {
#pragma unroll
    for (int nj = 0; nj < 4; ++nj) {
      const int col = bn + wc * 64 + nj * 16 + li;
#pragma unroll
      for (int r4 = 0; r4 < 4; ++r4) {
        const int row = bm + wr * 64 + mi * 16 + g * 4 + r4;
        C[(size_t)row * HD + col] = f2b(acc[mi][nj][r4]);
      }
    }
  }
  // fused attention-dot epilogue: head covered by this wave's 64 cols
  {
    const int head = (bn >> 6) + wc;  // 2*(j%6) + wc
    float aS[4], aD[4];
#pragma unroll
    for (int nj = 0; nj < 4; ++nj) {
      aS[nj] = att_src[head * Dv + nj * 16 + li];
      aD[nj] = att_dst[head * Dv + nj * 16 + li];
    }
#pragma unroll
    for (int mi = 0; mi < 4; ++mi) {
#pragma unroll
      for (int r4 = 0; r4 < 4; ++r4) {
        float vs = 0.f, vd = 0.f;
#pragma unroll
        for (int nj = 0; nj < 4; ++nj) {
          const float hv = acc[mi][nj][r4];
          vs = fmaf(hv, aS[nj], vs);
          vd = fmaf(hv, aD[nj], vd);
        }
        vs += __shfl_xor(vs, 1); vd += __shfl_xor(vd, 1);
        vs += __shfl_xor(vs, 2); vd += __shfl_xor(vd, 2);
        vs += __shfl_xor(vs, 4); vd += __shfl_xor(vd, 4);
        vs += __shfl_xor(vs, 8); vd += __shfl_xor(vd, 8);
        const int row = bm + wr * 64 + mi * 16 + g * 4 + r4;
        if (li == 0 && row < Mv) {
          asrc[(size_t)row * Hv + head] = vs;
          adst[(size_t)row * Hv + head] = vd;
        }
      }
    }
  }
}

// ------- fused softmax + aggregation: block per (b, n-pair) ----------------
// R15 version (best measured: 50.4us). 192 threads = 2 nodes x 96 lanes.
#define EDGE_FMA(c, wv)                                              \
  {                                                                  \
    acc[0] = fmaf(wv, __uint_as_float((c).x << 16), acc[0]);         \
    acc[1] = fmaf(wv, __uint_as_float((c).x & 0xFFFF0000u), acc[1]); \
    acc[2] = fmaf(wv, __uint_as_float((c).y << 16), acc[2]);         \
    acc[3] = fmaf(wv, __uint_as_float((c).y & 0xFFFF0000u), acc[3]); \
    acc[4] = fmaf(wv, __uint_as_float((c).z << 16), acc[4]);         \
    acc[5] = fmaf(wv, __uint_as_float((c).z & 0xFFFF0000u), acc[5]); \
    acc[6] = fmaf(wv, __uint_as_float((c).w << 16), acc[6]);         \
    acc[7] = fmaf(wv, __uint_as_float((c).w & 0xFFFF0000u), acc[7]); \
  }

__global__ __launch_bounds__(192) void k_agg(const unsigned short* __restrict__ h2,
                                             const int* __restrict__ cnt,
                                             const int* __restrict__ csrp,
                                             const float* __restrict__ asrc,
                                             const float* __restrict__ adst,
                                             const float* __restrict__ bias,
                                             float* __restrict__ out) {
  const int xcd = blockIdx.x & 7;
  const int idx = blockIdx.x >> 3;        // 0..624
  const int b = xcd >> 2;
  const int pair = (xcd & 3) * 625 + idx; // 0..2499
  const int n0 = pair * 2;                // block handles n0, n0+1
  const int t = threadIdx.x;
  __shared__ int s_src[2][DEGPAD];
  __shared__ float s_w[2][Hv][DEGW];
  __shared__ float s_inv[2][16];
  const int d0 = cnt[n0], d1 = cnt[n0 + 1];  // <= DEGMAX
  for (int i = t; i < 2 * DEGPAD; i += 192) {
    const int jn = i >= DEGPAD;
    const int ii = i - jn * DEGPAD;
    const int dd = jn ? d1 : d0;
    int sv = 0;
    if (ii < dd) sv = csrp[(n0 + jn) * DEGMAX + ii];
    s_src[jn][ii] = sv;  // pad with row 0 (safe to load, weight = 0)
  }
  __syncthreads();
  // Phase A: (node jn, head-quad q, slot): one f32x4 asrc load serves 4 heads
  {
    const int jn = t / 96, rq = t % 96;
    const int q = rq >> 5, slot = rq & 31;   // q = head quad (0..2)
    const int deg = jn ? d1 : d0;
    const int degp = (deg + 7) & ~7;
    const f32x4 adv4 = *(const f32x4*)&adst[((size_t)b * Nv + n0 + jn) * Hv + q * 4];
    f32x4 ps = {0.f, 0.f, 0.f, 0.f};
    for (int i = slot; i < deg; i += 32) {
      const int src = s_src[jn][i];
      const f32x4 as4 = *(const f32x4*)&asrc[((size_t)b * Nv + src) * Hv + q * 4];
#pragma unroll
      for (int jq = 0; jq < 4; ++jq) {
        float v = as4[jq] + adv4[jq];
        v = fmaxf(v, NEG * v);      // leaky_relu
        float ex = __expf(v);
        s_w[jn][q * 4 + jq][i] = ex;
        ps[jq] += ex;
      }
    }
    for (int i = deg + slot; i < degp; i += 32) {
#pragma unroll
      for (int jq = 0; jq < 4; ++jq) s_w[jn][q * 4 + jq][i] = 0.f;
    }
#pragma unroll
    for (int jq = 0; jq < 4; ++jq) {
      ps[jq] += __shfl_xor(ps[jq], 1);
      ps[jq] += __shfl_xor(ps[jq], 2);
      ps[jq] += __shfl_xor(ps[jq], 4);
      ps[jq] += __shfl_xor(ps[jq], 8);
      ps[jq] += __shfl_xor(ps[jq], 16);
    }
    if (slot == 0) {
      f32x4 inv;
#pragma unroll
      for (int jq = 0; jq < 4; ++jq) inv[jq] = 1.0f / (ps[jq] + 1e-16f);
      *(f32x4*)&s_inv[jn][q * 4] = inv;
    }
  }
  __syncthreads();
  // Phase B: node jn, lane tl owns dims [8tl, 8tl+8); no guards (0-padded w)
  const int jn = t >= 96;
  const int tl = t - jn * 96;
  const int hl = tl >> 3;  // head
  const int degp = ((jn ? d1 : d0) + 7) & ~7;
  float acc[8] = {};
  const unsigned short* hrow = h2 + (size_t)b * Nv * HD + tl * 8;
  uint4 cA[4], cB[4];
#pragma unroll
  for (int k = 0; k < 4; ++k)
    cA[k] = *(const uint4*)(hrow + (size_t)s_src[jn][k] * HD);
  for (int base = 0; base < degp; base += 8) {
#pragma unroll
    for (int k = 0; k < 4; ++k)
      cB[k] = *(const uint4*)(hrow + (size_t)s_src[jn][base + 4 + k] * HD);
    {
      const f32x4 w4 = *(const f32x4*)&s_w[jn][hl][base];
      EDGE_FMA(cA[0], w4[0]); EDGE_FMA(cA[1], w4[1]);
      EDGE_FMA(cA[2], w4[2]); EDGE_FMA(cA[3], w4[3]);
    }
#pragma unroll
    for (int k = 0; k < 4; ++k)
      cA[k] = *(const uint4*)(hrow + (size_t)s_src[jn][base + 8 + k] * HD);  // max 131 < DEGPAD
    {
      const f32x4 w4 = *(const f32x4*)&s_w[jn][hl][base + 4];
      EDGE_FMA(cB[0], w4[0]); EDGE_FMA(cB[1], w4[1]);
      EDGE_FMA(cB[2], w4[2]); EDGE_FMA(cB[3], w4[3]);
    }
  }
  const float invh = s_inv[jn][hl];
  const int od = tl * 8;
  float4 o0, o1;
  o0.x = fmaf(acc[0], invh, bias[od + 0]);
  o0.y = fmaf(acc[1], invh, bias[od + 1]);
  o0.z = fmaf(acc[2], invh, bias[od + 2]);
  o0.w = fmaf(acc[3], invh, bias[od + 3]);
  o1.x = fmaf(acc[4], invh, bias[od + 4]);
  o1.y = fmaf(acc[5], invh, bias[od + 5]);
  o1.z = fmaf(acc[6], invh, bias[od + 6]);
  o1.w = fmaf(acc[7], invh, bias[od + 7]);
  float* op = out + ((size_t)b * Nv + n0 + jn) * HD + od;
  *(float4*)op = o0;
  *(float4*)(op + 4) = o1;
}

extern "C" void kernel_launch(void* const* d_in, const int* in_sizes, int n_in,
                              void* d_out, int out_size, void* d_ws, size_t ws_size,
                              hipStream_t stream) {
  const float* x = (const float*)d_in[0];
  const float* W = (const float*)d_in[1];
  const float* att_src = (const float*)d_in[2];
  const float* att_dst = (const float*)d_in[3];
  const float* bias = (const float*)d_in[4];
  const int* ei = (const int*)d_in[5];
  float* out = (float*)d_out;

  // workspace layout (xbf eliminated)
  unsigned short* h2 = (unsigned short*)d_ws;            // MPAD*768 bf16
  unsigned short* wt = h2 + (size_t)MPAD * HD;           // 768*768 bf16
  float* asrc = (float*)(wt + (size_t)HD * Cv);          // 120,000 f32
  float* adst = asrc + (size_t)Bv * Nv * Hv;             // 120,000 f32
  int* cnt = (int*)(adst + (size_t)Bv * Nv * Hv);        // Nv (count AND cursor)
  int* csrp = cnt + Nv;                                  // Nv*DEGMAX padded CSR

  hipMemsetAsync(cnt, 0, sizeof(int) * Nv, stream);

  k_prep<<<NB_CVTW + NB_CNT, 256, 0, stream>>>(W, wt, ei, cnt, csrp);
  k_gemm_mfma<<<480, 256, 0, stream>>>(x, wt, h2, att_src, att_dst, asrc, adst);
  k_agg<<<Bv * Nv / 2, 192, 0, stream>>>(h2, cnt, csrp, asrc, adst, bias, out);
}

// Round 19
// 83.499 us; speedup vs baseline: 1.7170x; 1.1263x over previous
//
#include <hip/hip_runtime.h>

#define Bv 2
#define Nv 5000
#define Cv 768
#define Hv 12
#define Dv 64
#define Ev 160000
#define ETOT (Ev + Nv)   // 165000 (edges + self loops)
#define HD 768
#define NEG 0.2f
#define Mv (Bv * Nv)     // 10000
#define MPAD 10240       // 80 * 128
#define DEGMAX 128       // max in-degree incl. self-loop; Poisson(33) tail -> safe
#define DEGPAD 136       // staging pad so 4-deep prefetch can overread (max idx 131)
#define DEGW 132         // s_w edge stride: 4*33 keeps 16B align, spreads banks

typedef __bf16 bf16x8 __attribute__((ext_vector_type(8)));
typedef float f32x4 __attribute__((ext_vector_type(4)));

// direct-to-LDS 16B async copy
#define GLD16(gsrc, ldst)                                                      \
  __builtin_amdgcn_global_load_lds(                                            \
      (const __attribute__((address_space(1))) unsigned int*)(gsrc),           \
      (__attribute__((address_space(3))) unsigned int*)(ldst), 16, 0, 0)

// f32 -> bf16 round-to-nearest-even
__device__ __forceinline__ unsigned short f2b(float f) {
  unsigned u = __float_as_uint(f);
  return (unsigned short)((u + 0x7FFFu + ((u >> 16) & 1u)) >> 16);
}

// ---- pre: cvt_wt blocks + one cnt-zero block (replaces hipMemsetAsync) ----
#define NB_CVTW 576    // (768/32)*(768/32)
__global__ __launch_bounds__(256) void k_pre(const float* __restrict__ W,
                                             unsigned short* __restrict__ Wt,
                                             int* __restrict__ cnt) {
  const int blk = blockIdx.x;
  const int t = threadIdx.x;
  if (blk < NB_CVTW) {
    __shared__ float s[32][33];
    const int n0 = (blk % 24) * 32, k0 = (blk / 24) * 32;
    const int tx = t & 31, ty = t >> 5;  // 32 x 8
#pragma unroll
    for (int i = 0; i < 4; ++i)
      s[ty + i * 8][tx] = W[(size_t)(k0 + ty + i * 8) * HD + n0 + tx];
    __syncthreads();
#pragma unroll
    for (int i = 0; i < 4; ++i)
      Wt[(size_t)(n0 + ty + i * 8) * Cv + k0 + tx] = f2b(s[tx][ty + i * 8]);
  } else {
    for (int i = t; i < Nv; i += 256) cnt[i] = 0;
  }
}

// ------ GEMM (dbuf, fused x-cvt) + attn-dot epilogue + CSR side-blocks -----
// Blocks 0..479: 128x128 tile, 4 waves, DOUBLE-buffered LDS (64KB -> exactly
// the 2 blocks/CU this 480-block grid needs); stage(k+1) issued before
// compute(k), ONE barrier per K-step. A staged from f32 x with in-register
// cvt + swizzled ds_write; B via global_load_lds from wt.
// Blocks 480..1124: padded-dense-CSR build (independent; rides free).
#define NB_GEMM 480
#define NB_SCAT ((ETOT + 255) / 256)   // 645
#define STAGEG(bi, kk)                                                         \
  {                                                                            \
    _Pragma("unroll")                                                          \
    for (int i = 0; i < 4; ++i) {                                              \
      const int r = i * 32 + rs;                                               \
      GLD16(Bt + (size_t)(bn + r) * Cv + (kk) + sl * 8, &Bs[bi][t * 8 + i * 2048]); \
    }                                                                          \
    float4 av[4][2];                                                           \
    _Pragma("unroll")                                                          \
    for (int i = 0; i < 4; ++i) {                                              \
      const int grow = bm + i * 32 + rs;                                       \
      if (grow < Mv) {                                                         \
        const float* ap = Ax + (size_t)grow * Cv + (kk) + ssl * 8;             \
        av[i][0] = *(const float4*)ap;                                         \
        av[i][1] = *(const float4*)(ap + 4);                                   \
      } else {                                                                 \
        av[i][0] = make_float4(0.f, 0.f, 0.f, 0.f);                            \
        av[i][1] = av[i][0];                                                   \
      }                                                                        \
    }                                                                          \
    _Pragma("unroll")                                                          \
    for (int i = 0; i < 4; ++i) {                                              \
      const int r = i * 32 + rs;                                               \
      unsigned short o[8];                                                     \
      o[0] = f2b(av[i][0].x); o[1] = f2b(av[i][0].y);                          \
      o[2] = f2b(av[i][0].z); o[3] = f2b(av[i][0].w);                          \
      o[4] = f2b(av[i][1].x); o[5] = f2b(av[i][1].y);                          \
      o[6] = f2b(av[i][1].z); o[7] = f2b(av[i][1].w);                          \
      const int ds = ssl ^ (r & 7);                                            \
      *(uint4*)&As[bi][r * 64 + ds * 8] = *(const uint4*)o;                    \
    }                                                                          \
  }

__global__ __launch_bounds__(256) void k_gemm_sc(const float* __restrict__ Ax,
                                                 const unsigned short* __restrict__ Bt,
                                                 unsigned short* __restrict__ C,
                                                 const float* __restrict__ att_src,
                                                 const float* __restrict__ att_dst,
                                                 float* __restrict__ asrc,
                                                 float* __restrict__ adst,
                                                 const int* __restrict__ ei,
                                                 int* __restrict__ cnt,
                                                 int* __restrict__ csrp) {
  if (blockIdx.x >= NB_GEMM) {
    const int e = (blockIdx.x - NB_GEMM) * 256 + threadIdx.x;
    if (e < ETOT) {
      int dst = (e < Ev) ? ei[Ev + e] : (e - Ev);
      int src = (e < Ev) ? ei[e] : (e - Ev);
      int pos = atomicAdd(&cnt[dst], 1);
      csrp[dst * DEGMAX + pos] = src;
    }
    return;
  }
  __shared__ unsigned short As[2][128 * 64];
  __shared__ unsigned short Bs[2][128 * 64];
  const int l0 = blockIdx.x;
  const int xcd = l0 & 7, j = l0 >> 3;        // j < 60
  const int bm = (xcd + 8 * (j / 6)) * 128;   // M-block pinned to xcd (0..79)
  const int bn = (j % 6) * 128;
  const int t = threadIdx.x;
  const int w = t >> 6, l = t & 63;
  const int wr = w >> 1, wc = w & 1;          // 2 x 2 wave grid
  const int g = l >> 4, li = l & 15;
  f32x4 acc[4][4] = {};

  const int rs = t >> 3;              // staging row within 32-row issue (0..31)
  const int ssl = t & 7;              // logical k-slot (A reg-staging)
  const int sl = ssl ^ (rs & 7);      // pre-swizzled slot for B's linear GLD

  STAGEG(0, 0);
  __syncthreads();
  int cur = 0;
#pragma unroll 1
  for (int step = 0; step < Cv / 64; ++step) {
    if (step + 1 < Cv / 64) STAGEG(cur ^ 1, (step + 1) * 64);
#pragma unroll
    for (int ks = 0; ks < 2; ++ks) {
      bf16x8 a[4], b[4];
#pragma unroll
      for (int mi = 0; mi < 4; ++mi) {
        const int row = wr * 64 + mi * 16 + li;
        const int slot = (ks * 4 + g) ^ (row & 7);
        a[mi] = *(const bf16x8*)&As[cur][row * 64 + slot * 8];
      }
#pragma unroll
      for (int nj = 0; nj < 4; ++nj) {
        const int row = wc * 64 + nj * 16 + li;
        const int slot = (ks * 4 + g) ^ (row & 7);
        b[nj] = *(const bf16x8*)&Bs[cur][row * 64 + slot * 8];
      }
#pragma unroll
      for (int mi = 0; mi < 4; ++mi)
#pragma unroll
        for (int nj = 0; nj < 4; ++nj)
          acc[mi][nj] = __builtin_amdgcn_mfma_f32_16x16x32_bf16(a[mi], b[nj], acc[mi][nj], 0, 0, 0);
    }
    __syncthreads();  // drains ds_write+GLD of next buf; protects cur for reuse
    cur ^= 1;
  }
  // C/D layout: col = lane&15, row = (lane>>4)*4 + reg (m89-verified)
#pragma unroll
  for (int mi = 0; mi < 4; ++mi) {
#pragma unroll
    for (int nj = 0; nj < 4; ++nj) {
      const int col = bn + wc * 64 + nj * 16 + li;
#pragma unroll
      for (int r4 = 0; r4 < 4; ++r4) {
        const int row = bm + wr * 64 + mi * 16 + g * 4 + r4;
        C[(size_t)row * HD + col] = f2b(acc[mi][nj][r4]);
      }
    }
  }
  // fused attention-dot epilogue: head covered by this wave's 64 cols
  {
    const int head = (bn >> 6) + wc;  // 2*(j%6) + wc
    float aS[4], aD[4];
#pragma unroll
    for (int nj = 0; nj < 4; ++nj) {
      aS[nj] = att_src[head * Dv + nj * 16 + li];
      aD[nj] = att_dst[head * Dv + nj * 16 + li];
    }
#pragma unroll
    for (int mi = 0; mi < 4; ++mi) {
#pragma unroll
      for (int r4 = 0; r4 < 4; ++r4) {
        float vs = 0.f, vd = 0.f;
#pragma unroll
        for (int nj = 0; nj < 4; ++nj) {
          const float hv = acc[mi][nj][r4];
          vs = fmaf(hv, aS[nj], vs);
          vd = fmaf(hv, aD[nj], vd);
        }
        vs += __shfl_xor(vs, 1); vd += __shfl_xor(vd, 1);
        vs += __shfl_xor(vs, 2); vd += __shfl_xor(vd, 2);
        vs += __shfl_xor(vs, 4); vd += __shfl_xor(vd, 4);
        vs += __shfl_xor(vs, 8); vd += __shfl_xor(vd, 8);
        const int row = bm + wr * 64 + mi * 16 + g * 4 + r4;
        if (li == 0 && row < Mv) {
          asrc[(size_t)row * Hv + head] = vs;
          adst[(size_t)row * Hv + head] = vd;
        }
      }
    }
  }
}

// ------- fused softmax + aggregation: block per (b, n-pair) ----------------
// R15 version (best measured: 50.4us). 192 threads = 2 nodes x 96 lanes.
#define EDGE_FMA(c, wv)                                              \
  {                                                                  \
    acc[0] = fmaf(wv, __uint_as_float((c).x << 16), acc[0]);         \
    acc[1] = fmaf(wv, __uint_as_float((c).x & 0xFFFF0000u), acc[1]); \
    acc[2] = fmaf(wv, __uint_as_float((c).y << 16), acc[2]);         \
    acc[3] = fmaf(wv, __uint_as_float((c).y & 0xFFFF0000u), acc[3]); \
    acc[4] = fmaf(wv, __uint_as_float((c).z << 16), acc[4]);         \
    acc[5] = fmaf(wv, __uint_as_float((c).z & 0xFFFF0000u), acc[5]); \
    acc[6] = fmaf(wv, __uint_as_float((c).w << 16), acc[6]);         \
    acc[7] = fmaf(wv, __uint_as_float((c).w & 0xFFFF0000u), acc[7]); \
  }

__global__ __launch_bounds__(192) void k_agg(const unsigned short* __restrict__ h2,
                                             const int* __restrict__ cnt,
                                             const int* __restrict__ csrp,
                                             const float* __restrict__ asrc,
                                             const float* __restrict__ adst,
                                             const float* __restrict__ bias,
                                             float* __restrict__ out) {
  const int xcd = blockIdx.x & 7;
  const int idx = blockIdx.x >> 3;        // 0..624
  const int b = xcd >> 2;
  const int pair = (xcd & 3) * 625 + idx; // 0..2499
  const int n0 = pair * 2;                // block handles n0, n0+1
  const int t = threadIdx.x;
  __shared__ int s_src[2][DEGPAD];
  __shared__ float s_w[2][Hv][DEGW];
  __shared__ float s_inv[2][16];
  const int d0 = cnt[n0], d1 = cnt[n0 + 1];  // <= DEGMAX
  for (int i = t; i < 2 * DEGPAD; i += 192) {
    const int jn = i >= DEGPAD;
    const int ii = i - jn * DEGPAD;
    const int dd = jn ? d1 : d0;
    int sv = 0;
    if (ii < dd) sv = csrp[(n0 + jn) * DEGMAX + ii];
    s_src[jn][ii] = sv;  // pad with row 0 (safe to load, weight = 0)
  }
  __syncthreads();
  // Phase A: (node jn, head-quad q, slot): one f32x4 asrc load serves 4 heads
  {
    const int jn = t / 96, rq = t % 96;
    const int q = rq >> 5, slot = rq & 31;   // q = head quad (0..2)
    const int deg = jn ? d1 : d0;
    const int degp = (deg + 7) & ~7;
    const f32x4 adv4 = *(const f32x4*)&adst[((size_t)b * Nv + n0 + jn) * Hv + q * 4];
    f32x4 ps = {0.f, 0.f, 0.f, 0.f};
    for (int i = slot; i < deg; i += 32) {
      const int src = s_src[jn][i];
      const f32x4 as4 = *(const f32x4*)&asrc[((size_t)b * Nv + src) * Hv + q * 4];
#pragma unroll
      for (int jq = 0; jq < 4; ++jq) {
        float v = as4[jq] + adv4[jq];
        v = fmaxf(v, NEG * v);      // leaky_relu
        float ex = __expf(v);
        s_w[jn][q * 4 + jq][i] = ex;
        ps[jq] += ex;
      }
    }
    for (int i = deg + slot; i < degp; i += 32) {
#pragma unroll
      for (int jq = 0; jq < 4; ++jq) s_w[jn][q * 4 + jq][i] = 0.f;
    }
#pragma unroll
    for (int jq = 0; jq < 4; ++jq) {
      ps[jq] += __shfl_xor(ps[jq], 1);
      ps[jq] += __shfl_xor(ps[jq], 2);
      ps[jq] += __shfl_xor(ps[jq], 4);
      ps[jq] += __shfl_xor(ps[jq], 8);
      ps[jq] += __shfl_xor(ps[jq], 16);
    }
    if (slot == 0) {
      f32x4 inv;
#pragma unroll
      for (int jq = 0; jq < 4; ++jq) inv[jq] = 1.0f / (ps[jq] + 1e-16f);
      *(f32x4*)&s_inv[jn][q * 4] = inv;
    }
  }
  __syncthreads();
  // Phase B: node jn, lane tl owns dims [8tl, 8tl+8); no guards (0-padded w)
  const int jn = t >= 96;
  const int tl = t - jn * 96;
  const int hl = tl >> 3;  // head
  const int degp = ((jn ? d1 : d0) + 7) & ~7;
  float acc[8] = {};
  const unsigned short* hrow = h2 + (size_t)b * Nv * HD + tl * 8;
  uint4 cA[4], cB[4];
#pragma unroll
  for (int k = 0; k < 4; ++k)
    cA[k] = *(const uint4*)(hrow + (size_t)s_src[jn][k] * HD);
  for (int base = 0; base < degp; base += 8) {
#pragma unroll
    for (int k = 0; k < 4; ++k)
      cB[k] = *(const uint4*)(hrow + (size_t)s_src[jn][base + 4 + k] * HD);
    {
      const f32x4 w4 = *(const f32x4*)&s_w[jn][hl][base];
      EDGE_FMA(cA[0], w4[0]); EDGE_FMA(cA[1], w4[1]);
      EDGE_FMA(cA[2], w4[2]); EDGE_FMA(cA[3], w4[3]);
    }
#pragma unroll
    for (int k = 0; k < 4; ++k)
      cA[k] = *(const uint4*)(hrow + (size_t)s_src[jn][base + 8 + k] * HD);  // max 131 < DEGPAD
    {
      const f32x4 w4 = *(const f32x4*)&s_w[jn][hl][base + 4];
      EDGE_FMA(cB[0], w4[0]); EDGE_FMA(cB[1], w4[1]);
      EDGE_FMA(cB[2], w4[2]); EDGE_FMA(cB[3], w4[3]);
    }
  }
  const float invh = s_inv[jn][hl];
  const int od = tl * 8;
  float4 o0, o1;
  o0.x = fmaf(acc[0], invh, bias[od + 0]);
  o0.y = fmaf(acc[1], invh, bias[od + 1]);
  o0.z = fmaf(acc[2], invh, bias[od + 2]);
  o0.w = fmaf(acc[3], invh, bias[od + 3]);
  o1.x = fmaf(acc[4], invh, bias[od + 4]);
  o1.y = fmaf(acc[5], invh, bias[od + 5]);
  o1.z = fmaf(acc[6], invh, bias[od + 6]);
  o1.w = fmaf(acc[7], invh, bias[od + 7]);
  float* op = out + ((size_t)b * Nv + n0 + jn) * HD + od;
  *(float4*)op = o0;
  *(float4*)(op + 4) = o1;
}

extern "C" void kernel_launch(void* const* d_in, const int* in_sizes, int n_in,
                              void* d_out, int out_size, void* d_ws, size_t ws_size,
                              hipStream_t stream) {
  const float* x = (const float*)d_in[0];
  const float* W = (const float*)d_in[1];
  const float* att_src = (const float*)d_in[2];
  const float* att_dst = (const float*)d_in[3];
  const float* bias = (const float*)d_in[4];
  const int* ei = (const int*)d_in[5];
  float* out = (float*)d_out;

  // workspace layout
  unsigned short* h2 = (unsigned short*)d_ws;            // MPAD*768 bf16
  unsigned short* wt = h2 + (size_t)MPAD * HD;           // 768*768 bf16
  float* asrc = (float*)(wt + (size_t)HD * Cv);          // 120,000 f32
  float* adst = asrc + (size_t)Bv * Nv * Hv;             // 120,000 f32
  int* cnt = (int*)(adst + (size_t)Bv * Nv * Hv);        // Nv (count AND cursor)
  int* csrp = cnt + Nv;                                  // Nv*DEGMAX padded CSR

  k_pre<<<NB_CVTW + 1, 256, 0, stream>>>(W, wt, cnt);
  k_gemm_sc<<<NB_GEMM + NB_SCAT, 256, 0, stream>>>(x, wt, h2, att_src, att_dst,
                                                   asrc, adst, ei, cnt, csrp);
  k_agg<<<Bv * Nv / 2, 192, 0, stream>>>(h2, cnt, csrp, asrc, adst, bias, out);
}